// Round 2
// baseline (873.683 us; speedup 1.0000x reference)
//
#include <hip/hip_runtime.h>

// ---------------------------------------------------------------------------
// GIN inference: 5 GIN layers (agg + 2-layer MLP + BN) + global_add_pool + head
// Round 1: fp32 baseline, macro bug fixed (FMA4 macro param `w` collided with
// member accessor .w -> inline function instead).
// ---------------------------------------------------------------------------

// ---------------- CSR build ----------------

__global__ void deg_count(const int* __restrict__ dst, int* __restrict__ deg, int E) {
    int e = blockIdx.x * 256 + threadIdx.x;
    if (e < E) atomicAdd(&deg[dst[e]], 1);
}

__global__ void block_sum(const int* __restrict__ deg, int* __restrict__ bsum, int N) {
    __shared__ int s[256];
    int tid = threadIdx.x;
    int i = blockIdx.x * 256 + tid;
    s[tid] = (i < N) ? deg[i] : 0;
    __syncthreads();
    for (int off = 128; off > 0; off >>= 1) {
        if (tid < off) s[tid] += s[tid + off];
        __syncthreads();
    }
    if (tid == 0) bsum[blockIdx.x] = s[0];
}

// single block, NB <= 256: exclusive scan of bsum in place
__global__ void scan_bsum(int* bsum, int NB) {
    __shared__ int s[256];
    int tid = threadIdx.x;
    int v = (tid < NB) ? bsum[tid] : 0;
    s[tid] = v;
    __syncthreads();
    for (int off = 1; off < 256; off <<= 1) {
        int t = (tid >= off) ? s[tid - off] : 0;
        __syncthreads();
        s[tid] += t;
        __syncthreads();
    }
    if (tid < NB) bsum[tid] = s[tid] - v;   // exclusive
}

__global__ void make_rowptr(const int* __restrict__ deg, const int* __restrict__ boff,
                            int* __restrict__ rowptr, int* __restrict__ cur, int N) {
    __shared__ int s[256];
    int tid = threadIdx.x;
    int i = blockIdx.x * 256 + tid;
    int v = (i < N) ? deg[i] : 0;
    s[tid] = v;
    __syncthreads();
    for (int off = 1; off < 256; off <<= 1) {
        int t = (tid >= off) ? s[tid - off] : 0;
        __syncthreads();
        s[tid] += t;
        __syncthreads();
    }
    int excl = s[tid] - v;
    int off0 = boff[blockIdx.x];
    if (i < N) {
        rowptr[i] = off0 + excl;
        cur[i]    = off0 + excl;
    }
    if (i == N - 1) rowptr[N] = off0 + s[tid];
}

__global__ void fill_col(const int* __restrict__ src, const int* __restrict__ dst,
                         int* __restrict__ cur, int* __restrict__ col, int E) {
    int e = blockIdx.x * 256 + threadIdx.x;
    if (e < E) {
        int p = atomicAdd(&cur[dst[e]], 1);
        col[p] = src[e];
    }
}

// ---------------- layer 1 (input dim = 2) ----------------

__global__ void agg2(const float* __restrict__ x, const int* __restrict__ rowptr,
                     const int* __restrict__ col, float* __restrict__ sum2, int N) {
    int n = blockIdx.x * 256 + threadIdx.x;
    if (n >= N) return;
    float ax = x[2 * n], ay = x[2 * n + 1];
    int e0 = rowptr[n], e1 = rowptr[n + 1];
    for (int j = e0; j < e1; ++j) {
        int s = col[j];
        ax += x[2 * s];
        ay += x[2 * s + 1];
    }
    sum2[2 * n] = ax;
    sum2[2 * n + 1] = ay;
}

__global__ void mlp1a(const float* __restrict__ sum2, const float* __restrict__ W1,
                      const float* __restrict__ b1, float* __restrict__ out, int N) {
    int idx = blockIdx.x * 256 + threadIdx.x;
    if (idx >= N * 128) return;
    int n = idx >> 7, c = idx & 127;
    float v = fmaf(sum2[2 * n], W1[c], fmaf(sum2[2 * n + 1], W1[128 + c], b1[c]));
    out[idx] = fmaxf(v, 0.f);
}

// ---------------- aggregation, H=128: one wave per node ----------------

__global__ void aggH(const float* __restrict__ h, const int* __restrict__ rowptr,
                     const int* __restrict__ col, float* __restrict__ out, int N) {
    int n = blockIdx.x * 4 + (threadIdx.x >> 6);
    if (n >= N) return;
    int l = threadIdx.x & 63;
    const float2* h2 = (const float2*)h;
    float2 acc = h2[(size_t)n * 64 + l];
    int e0 = rowptr[n], e1 = rowptr[n + 1];
    for (int j = e0; j < e1; ++j) {
        int s = col[j];
        float2 v = h2[(size_t)s * 64 + l];
        acc.x += v.x;
        acc.y += v.y;
    }
    ((float2*)out)[(size_t)n * 64 + l] = acc;
}

// ---------------- [N,128] @ [128,128] + bias + relu (+ optional BN) ----------------
// tile: 64 rows x 128 cols, BK=32 LDS slabs. 256 threads, micro-tile 8 rows x 4 cols.

__device__ __forceinline__ void fma4(float4& acc, float s, const float4& ww) {
    acc.x = fmaf(s, ww.x, acc.x);
    acc.y = fmaf(s, ww.y, acc.y);
    acc.z = fmaf(s, ww.z, acc.z);
    acc.w = fmaf(s, ww.w, acc.w);
}

__launch_bounds__(256)
__global__ void gemm_mlp(const float* __restrict__ A, const float* __restrict__ W,
                         const float* __restrict__ bias,
                         const float* __restrict__ gamma, const float* __restrict__ beta,
                         const float* __restrict__ mean, const float* __restrict__ var,
                         float* __restrict__ out, int N) {
    __shared__ float As[64][36];   // padded stride 36: breaks bank aliasing, keeps 16B align
    __shared__ float Ws[32][128];
    int tid = threadIdx.x;
    int cg = tid & 31;   // cols cg*4 .. cg*4+3
    int rg = tid >> 5;   // rows rg*8 .. rg*8+7
    int base = blockIdx.x * 64;

    float4 acc[8];
#pragma unroll
    for (int i = 0; i < 8; ++i) acc[i] = make_float4(0.f, 0.f, 0.f, 0.f);

    for (int ks = 0; ks < 128; ks += 32) {
        // stage A slab: 64 x 32
#pragma unroll
        for (int i = 0; i < 2; ++i) {
            int idx = i * 1024 + tid * 4;
            int r = idx >> 5, c = idx & 31;
            float4 v = make_float4(0.f, 0.f, 0.f, 0.f);
            if (base + r < N) v = *(const float4*)&A[(size_t)(base + r) * 128 + ks + c];
            *(float4*)&As[r][c] = v;
        }
        // stage W slab: 32 x 128
#pragma unroll
        for (int i = 0; i < 4; ++i) {
            int idx = i * 1024 + tid * 4;
            int kr = idx >> 7, c = idx & 127;
            *(float4*)&Ws[kr][c] = *(const float4*)&W[(size_t)(ks + kr) * 128 + c];
        }
        __syncthreads();
#pragma unroll
        for (int kk = 0; kk < 32; kk += 4) {
            float4 w0 = *(const float4*)&Ws[kk + 0][cg * 4];
            float4 w1 = *(const float4*)&Ws[kk + 1][cg * 4];
            float4 w2 = *(const float4*)&Ws[kk + 2][cg * 4];
            float4 w3 = *(const float4*)&Ws[kk + 3][cg * 4];
#pragma unroll
            for (int i = 0; i < 8; ++i) {
                float4 a = *(const float4*)&As[rg * 8 + i][kk];
                fma4(acc[i], a.x, w0);
                fma4(acc[i], a.y, w1);
                fma4(acc[i], a.z, w2);
                fma4(acc[i], a.w, w3);
            }
        }
        __syncthreads();
    }

    int c0 = cg * 4;
    float4 b4 = *(const float4*)&bias[c0];
    float4 sc = make_float4(1.f, 1.f, 1.f, 1.f);
    float4 sh = make_float4(0.f, 0.f, 0.f, 0.f);
    bool bn = (gamma != nullptr);
    if (bn) {
        float4 g4 = *(const float4*)&gamma[c0];
        float4 be = *(const float4*)&beta[c0];
        float4 m4 = *(const float4*)&mean[c0];
        float4 v4 = *(const float4*)&var[c0];
        sc.x = g4.x * rsqrtf(v4.x + 1e-5f); sh.x = be.x - m4.x * sc.x;
        sc.y = g4.y * rsqrtf(v4.y + 1e-5f); sh.y = be.y - m4.y * sc.y;
        sc.z = g4.z * rsqrtf(v4.z + 1e-5f); sh.z = be.z - m4.z * sc.z;
        sc.w = g4.w * rsqrtf(v4.w + 1e-5f); sh.w = be.w - m4.w * sc.w;
    }
#pragma unroll
    for (int i = 0; i < 8; ++i) {
        int r = base + rg * 8 + i;
        if (r < N) {
            float4 v;
            v.x = fmaxf(acc[i].x + b4.x, 0.f);
            v.y = fmaxf(acc[i].y + b4.y, 0.f);
            v.z = fmaxf(acc[i].z + b4.z, 0.f);
            v.w = fmaxf(acc[i].w + b4.w, 0.f);
            if (bn) {
                v.x = fmaf(v.x, sc.x, sh.x);
                v.y = fmaf(v.y, sc.y, sh.y);
                v.z = fmaf(v.z, sc.z, sh.z);
                v.w = fmaf(v.w, sc.w, sh.w);
            }
            *(float4*)&out[(size_t)r * 128 + c0] = v;
        }
    }
}

// ---------------- pooling (sorted batch) + MLP head, one block per graph ----------------

__global__ void pool_head(const float* __restrict__ h, const int* __restrict__ batch,
                          const float* __restrict__ lin1W, const float* __restrict__ lin1b,
                          const float* __restrict__ lin2W, const float* __restrict__ lin2b,
                          float* __restrict__ out, int N) {
    int g = blockIdx.x;
    int c = threadIdx.x;  // 0..127
    // binary search run boundaries in sorted batch
    int lo = 0, hi = N;
    while (lo < hi) { int m = (lo + hi) >> 1; if (batch[m] < g) lo = m + 1; else hi = m; }
    int start = lo;
    lo = start; hi = N;
    while (lo < hi) { int m = (lo + hi) >> 1; if (batch[m] < g + 1) lo = m + 1; else hi = m; }
    int end = lo;

    float acc = 0.f;
    for (int n = start; n < end; ++n) acc += h[(size_t)n * 128 + c];

    __shared__ float pl[128];
    pl[c] = acc;
    __syncthreads();

    float o = lin1b[c];
    for (int k = 0; k < 128; ++k) o = fmaf(pl[k], lin1W[k * 128 + c], o);
    o = fmaxf(o, 0.f) * lin2W[c];

    __shared__ float red[128];
    red[c] = o;
    __syncthreads();
    for (int off = 64; off > 0; off >>= 1) {
        if (c < off) red[c] += red[c + off];
        __syncthreads();
    }
    if (c == 0) out[g] = red[0] + lin2b[0];
}

// ---------------------------------------------------------------------------

extern "C" void kernel_launch(void* const* d_in, const int* in_sizes, int n_in,
                              void* d_out, int out_size, void* d_ws, size_t ws_size,
                              hipStream_t stream) {
    const float* x     = (const float*)d_in[0];
    const int*   ei    = (const int*)d_in[1];
    const int*   batch = (const int*)d_in[2];
    const float* c1W1  = (const float*)d_in[3];
    const float* c1b1  = (const float*)d_in[4];
    const float* c1W2  = (const float*)d_in[5];
    const float* c1b2  = (const float*)d_in[6];
    const float* c1g   = (const float*)d_in[7];
    const float* c1be  = (const float*)d_in[8];
    const float* c1m   = (const float*)d_in[9];
    const float* c1v   = (const float*)d_in[10];
    const float* csW1  = (const float*)d_in[11];
    const float* csb1  = (const float*)d_in[12];
    const float* csW2  = (const float*)d_in[13];
    const float* csb2  = (const float*)d_in[14];
    const float* csg   = (const float*)d_in[15];
    const float* csbe  = (const float*)d_in[16];
    const float* csm   = (const float*)d_in[17];
    const float* csv   = (const float*)d_in[18];
    const float* lin1W = (const float*)d_in[19];
    const float* lin1b = (const float*)d_in[20];
    const float* lin2W = (const float*)d_in[21];
    const float* lin2b = (const float*)d_in[22];

    const int N = in_sizes[0] / 2;
    const int E = in_sizes[1] / 2;
    const int G = out_size;
    const int NL = in_sizes[11] / (128 * 128);  // 4

    char* ws = (char*)d_ws;
    size_t SZH = (size_t)N * 128 * sizeof(float);
    float* h    = (float*)(ws);
    float* sum  = (float*)(ws + SZH);
    float* tmp  = (float*)(ws + 2 * SZH);
    float* sum2 = (float*)(ws + 3 * SZH);
    char* p = ws + 3 * SZH + (((size_t)N * 2 * 4 + 15) / 16) * 16;
    int* deg = (int*)p;    p += (((size_t)N * 4 + 15) / 16) * 16;
    int* cur = (int*)p;    p += (((size_t)N * 4 + 15) / 16) * 16;
    int* rowptr = (int*)p; p += (((size_t)(N + 1) * 4 + 15) / 16) * 16;
    int* bsum = (int*)p;   p += 1024;
    int* col = (int*)p;

    const int* srcI = ei;
    const int* dstI = ei + E;

    const int NB = (N + 255) / 256;
    const int EB = (E + 255) / 256;
    const int GB = (N + 63) / 64;

    (void)hipMemsetAsync(deg, 0, (size_t)N * 4, stream);
    deg_count<<<EB, 256, 0, stream>>>(dstI, deg, E);
    block_sum<<<NB, 256, 0, stream>>>(deg, bsum, N);
    scan_bsum<<<1, 256, 0, stream>>>(bsum, NB);
    make_rowptr<<<NB, 256, 0, stream>>>(deg, bsum, rowptr, cur, N);
    fill_col<<<EB, 256, 0, stream>>>(srcI, dstI, cur, col, E);

    // layer 1 (input dim 2)
    agg2<<<NB, 256, 0, stream>>>(x, rowptr, col, sum2, N);
    mlp1a<<<(N * 128 + 255) / 256, 256, 0, stream>>>(sum2, c1W1, c1b1, tmp, N);
    gemm_mlp<<<GB, 256, 0, stream>>>(tmp, c1W2, c1b2, c1g, c1be, c1m, c1v, h, N);

    // layers 2..5
    for (int i = 0; i < NL; ++i) {
        aggH<<<(N + 3) / 4, 256, 0, stream>>>(h, rowptr, col, sum, N);
        gemm_mlp<<<GB, 256, 0, stream>>>(sum, csW1 + (size_t)i * 16384, csb1 + i * 128,
                                         nullptr, nullptr, nullptr, nullptr, tmp, N);
        gemm_mlp<<<GB, 256, 0, stream>>>(tmp, csW2 + (size_t)i * 16384, csb2 + i * 128,
                                         csg + i * 128, csbe + i * 128, csm + i * 128,
                                         csv + i * 128, h, N);
    }

    pool_head<<<G, 128, 0, stream>>>(h, batch, lin1W, lin1b, lin2W, lin2b, (float*)d_out, N);
}

// Round 3
// 710.692 us; speedup vs baseline: 1.2293x; 1.2293x over previous
//
#include <hip/hip_runtime.h>

// ---------------------------------------------------------------------------
// GIN inference, round 2: bf16 feature storage (halves gather traffic) +
// bf16 MFMA GEMMs (mfma_f32_16x16x32_bf16, fp32 accumulate), weights packed
// per-call into B-fragment layout. CSR-by-dst gather aggregation as before.
// ---------------------------------------------------------------------------

typedef __attribute__((ext_vector_type(8))) short short8;   // 8 bf16 (4 VGPRs)
typedef __attribute__((ext_vector_type(4))) float floatx4;  // 4 fp32 acc

__device__ __forceinline__ unsigned short f2bf(float f) {
    unsigned u = __float_as_uint(f);
    unsigned r = (u + 0x7fffu + ((u >> 16) & 1u)) >> 16;   // RNE
    return (unsigned short)r;
}
__device__ __forceinline__ float bf2f(unsigned short b) {
    return __uint_as_float(((unsigned)b) << 16);
}

// ---------------- CSR build ----------------

__global__ void deg_count(const int* __restrict__ dst, int* __restrict__ deg, int E) {
    int e = blockIdx.x * 256 + threadIdx.x;
    if (e < E) atomicAdd(&deg[dst[e]], 1);
}

__global__ void block_sum(const int* __restrict__ deg, int* __restrict__ bsum, int N) {
    __shared__ int s[256];
    int tid = threadIdx.x;
    int i = blockIdx.x * 256 + tid;
    s[tid] = (i < N) ? deg[i] : 0;
    __syncthreads();
    for (int off = 128; off > 0; off >>= 1) {
        if (tid < off) s[tid] += s[tid + off];
        __syncthreads();
    }
    if (tid == 0) bsum[blockIdx.x] = s[0];
}

__global__ void scan_bsum(int* bsum, int NB) {
    __shared__ int s[256];
    int tid = threadIdx.x;
    int v = (tid < NB) ? bsum[tid] : 0;
    s[tid] = v;
    __syncthreads();
    for (int off = 1; off < 256; off <<= 1) {
        int t = (tid >= off) ? s[tid - off] : 0;
        __syncthreads();
        s[tid] += t;
        __syncthreads();
    }
    if (tid < NB) bsum[tid] = s[tid] - v;   // exclusive
}

__global__ void make_rowptr(const int* __restrict__ deg, const int* __restrict__ boff,
                            int* __restrict__ rowptr, int* __restrict__ cur, int N) {
    __shared__ int s[256];
    int tid = threadIdx.x;
    int i = blockIdx.x * 256 + tid;
    int v = (i < N) ? deg[i] : 0;
    s[tid] = v;
    __syncthreads();
    for (int off = 1; off < 256; off <<= 1) {
        int t = (tid >= off) ? s[tid - off] : 0;
        __syncthreads();
        s[tid] += t;
        __syncthreads();
    }
    int excl = s[tid] - v;
    int off0 = boff[blockIdx.x];
    if (i < N) {
        rowptr[i] = off0 + excl;
        cur[i]    = off0 + excl;
    }
    if (i == N - 1) rowptr[N] = off0 + s[tid];
}

__global__ void fill_col(const int* __restrict__ src, const int* __restrict__ dst,
                         int* __restrict__ cur, int* __restrict__ col, int E) {
    int e = blockIdx.x * 256 + threadIdx.x;
    if (e < E) {
        int p = atomicAdd(&cur[dst[e]], 1);
        col[p] = src[e];
    }
}

// ---------------- weight packing: W[128][128] fp32 -> B-frag bf16 layout -----
// Wp[((ks*8 + nt)*64 + lane)*8 + j] = bf16(W[ks*32 + (lane>>4)*8 + j][nt*16 + (lane&15)])

__global__ void pack_W(const float* __restrict__ W, unsigned short* __restrict__ Wp) {
    int r = blockIdx.x * 256 + threadIdx.x;          // 0..16383
    int j = r & 7, lane = (r >> 3) & 63, nt = (r >> 9) & 7, ks = (r >> 12) & 3;
    int k = ks * 32 + (lane >> 4) * 8 + j;
    int n = nt * 16 + (lane & 15);
    Wp[r] = f2bf(W[k * 128 + n]);
}

// ---------------- layer 1 (input dim = 2) ----------------

__global__ void agg2(const float* __restrict__ x, const int* __restrict__ rowptr,
                     const int* __restrict__ col, float* __restrict__ sum2, int N) {
    int n = blockIdx.x * 256 + threadIdx.x;
    if (n >= N) return;
    float ax = x[2 * n], ay = x[2 * n + 1];
    int e0 = rowptr[n], e1 = rowptr[n + 1];
    for (int j = e0; j < e1; ++j) {
        int s = col[j];
        ax += x[2 * s];
        ay += x[2 * s + 1];
    }
    sum2[2 * n] = ax;
    sum2[2 * n + 1] = ay;
}

__global__ void mlp1a(const float* __restrict__ sum2, const float* __restrict__ W1,
                      const float* __restrict__ b1, unsigned short* __restrict__ out, int N) {
    int idx = blockIdx.x * 256 + threadIdx.x;
    if (idx >= N * 128) return;
    int n = idx >> 7, c = idx & 127;
    float v = fmaf(sum2[2 * n], W1[c], fmaf(sum2[2 * n + 1], W1[128 + c], b1[c]));
    out[idx] = f2bf(fmaxf(v, 0.f));
}

// ---------------- aggregation, bf16 rows of 256 B: one wave per node --------

__global__ void aggH_bf16(const unsigned* __restrict__ h2, const int* __restrict__ rowptr,
                          const int* __restrict__ col, unsigned* __restrict__ out2, int N) {
    int n = blockIdx.x * 4 + (threadIdx.x >> 6);
    if (n >= N) return;
    int l = threadIdx.x & 63;
    unsigned self = h2[(size_t)n * 64 + l];
    float ax = __uint_as_float(self << 16);
    float ay = __uint_as_float(self & 0xffff0000u);
    int e0 = rowptr[n], e1 = rowptr[n + 1];
    for (int j = e0; j < e1; ++j) {
        int s = col[j];
        unsigned v = h2[(size_t)s * 64 + l];
        ax += __uint_as_float(v << 16);
        ay += __uint_as_float(v & 0xffff0000u);
    }
    out2[(size_t)n * 64 + l] = (unsigned)f2bf(ax) | ((unsigned)f2bf(ay) << 16);
}

// ---------------- [N,128] @ [128,128] bf16 MFMA + bias + relu (+BN) ---------
// 256 threads = 4 waves; wave w handles rows row0..row0+15, all 128 cols.
// A-frag: lane holds A[row0 + (lane&15)][ks*32 + (lane>>4)*8 + j], j=0..7.
// B-frag from packed Wp (contiguous per lane). C/D: col=lane&15, row=(lane>>4)*4+reg.

__launch_bounds__(256)
__global__ void gemm_mfma(const unsigned short* __restrict__ A,
                          const unsigned short* __restrict__ Wp,
                          const float* __restrict__ bias,
                          const float* __restrict__ gamma, const float* __restrict__ beta,
                          const float* __restrict__ mean, const float* __restrict__ var,
                          unsigned short* __restrict__ out, int N) {
    int wave = threadIdx.x >> 6, lane = threadIdx.x & 63;
    int row0 = blockIdx.x * 64 + wave * 16;
    if (row0 >= N) return;
    int m = lane & 15, q = lane >> 4;
    int arow = row0 + m;
    if (arow > N - 1) arow = N - 1;   // clamp: invalid rows masked at store

    const short8 a0 = *(const short8*)&A[(size_t)arow * 128 + 0 * 32 + q * 8];
    const short8 a1 = *(const short8*)&A[(size_t)arow * 128 + 1 * 32 + q * 8];
    const short8 a2 = *(const short8*)&A[(size_t)arow * 128 + 2 * 32 + q * 8];
    const short8 a3 = *(const short8*)&A[(size_t)arow * 128 + 3 * 32 + q * 8];

    floatx4 acc[8];
#pragma unroll
    for (int nt = 0; nt < 8; ++nt) acc[nt] = (floatx4){0.f, 0.f, 0.f, 0.f};

#pragma unroll
    for (int nt = 0; nt < 8; ++nt) {
        short8 b0 = *(const short8*)&Wp[((0 * 8 + nt) * 64 + lane) * 8];
        short8 b1 = *(const short8*)&Wp[((1 * 8 + nt) * 64 + lane) * 8];
        short8 b2 = *(const short8*)&Wp[((2 * 8 + nt) * 64 + lane) * 8];
        short8 b3 = *(const short8*)&Wp[((3 * 8 + nt) * 64 + lane) * 8];
        acc[nt] = __builtin_amdgcn_mfma_f32_16x16x32_bf16(a0, b0, acc[nt], 0, 0, 0);
        acc[nt] = __builtin_amdgcn_mfma_f32_16x16x32_bf16(a1, b1, acc[nt], 0, 0, 0);
        acc[nt] = __builtin_amdgcn_mfma_f32_16x16x32_bf16(a2, b2, acc[nt], 0, 0, 0);
        acc[nt] = __builtin_amdgcn_mfma_f32_16x16x32_bf16(a3, b3, acc[nt], 0, 0, 0);
    }

    int ct = lane & 15, rb = q * 4;
    bool bn = (gamma != nullptr);
#pragma unroll
    for (int nt = 0; nt < 8; ++nt) {
        int colc = nt * 16 + ct;
        float bi = bias[colc];
        float scl = 1.f, shf = 0.f;
        if (bn) {
            float g = gamma[colc], be = beta[colc], me = mean[colc], va = var[colc];
            scl = g * rsqrtf(va + 1e-5f);
            shf = be - me * scl;
        }
#pragma unroll
        for (int rg = 0; rg < 4; ++rg) {
            int rr = row0 + rb + rg;
            if (rr < N) {
                float v = fmaxf(acc[nt][rg] + bi, 0.f);
                v = fmaf(v, scl, shf);
                out[(size_t)rr * 128 + colc] = f2bf(v);
            }
        }
    }
}

// ---------------- pooling (sorted batch) + MLP head, one block per graph ----

__global__ void pool_head(const unsigned short* __restrict__ h, const int* __restrict__ batch,
                          const float* __restrict__ lin1W, const float* __restrict__ lin1b,
                          const float* __restrict__ lin2W, const float* __restrict__ lin2b,
                          float* __restrict__ out, int N) {
    int g = blockIdx.x;
    int c = threadIdx.x;  // 0..127
    int lo = 0, hi = N;
    while (lo < hi) { int m = (lo + hi) >> 1; if (batch[m] < g) lo = m + 1; else hi = m; }
    int start = lo;
    lo = start; hi = N;
    while (lo < hi) { int m = (lo + hi) >> 1; if (batch[m] < g + 1) lo = m + 1; else hi = m; }
    int end = lo;

    float acc = 0.f;
    for (int n = start; n < end; ++n) acc += bf2f(h[(size_t)n * 128 + c]);

    __shared__ float pl[128];
    pl[c] = acc;
    __syncthreads();

    float o = lin1b[c];
    for (int k = 0; k < 128; ++k) o = fmaf(pl[k], lin1W[k * 128 + c], o);
    o = fmaxf(o, 0.f) * lin2W[c];

    __shared__ float red[128];
    red[c] = o;
    __syncthreads();
    for (int off = 64; off > 0; off >>= 1) {
        if (c < off) red[c] += red[c + off];
        __syncthreads();
    }
    if (c == 0) out[g] = red[0] + lin2b[0];
}

// ---------------------------------------------------------------------------

extern "C" void kernel_launch(void* const* d_in, const int* in_sizes, int n_in,
                              void* d_out, int out_size, void* d_ws, size_t ws_size,
                              hipStream_t stream) {
    const float* x     = (const float*)d_in[0];
    const int*   ei    = (const int*)d_in[1];
    const int*   batch = (const int*)d_in[2];
    const float* c1W1  = (const float*)d_in[3];
    const float* c1b1  = (const float*)d_in[4];
    const float* c1W2  = (const float*)d_in[5];
    const float* c1b2  = (const float*)d_in[6];
    const float* c1g   = (const float*)d_in[7];
    const float* c1be  = (const float*)d_in[8];
    const float* c1m   = (const float*)d_in[9];
    const float* c1v   = (const float*)d_in[10];
    const float* csW1  = (const float*)d_in[11];
    const float* csb1  = (const float*)d_in[12];
    const float* csW2  = (const float*)d_in[13];
    const float* csb2  = (const float*)d_in[14];
    const float* csg   = (const float*)d_in[15];
    const float* csbe  = (const float*)d_in[16];
    const float* csm   = (const float*)d_in[17];
    const float* csv   = (const float*)d_in[18];
    const float* lin1W = (const float*)d_in[19];
    const float* lin1b = (const float*)d_in[20];
    const float* lin2W = (const float*)d_in[21];
    const float* lin2b = (const float*)d_in[22];

    const int N = in_sizes[0] / 2;
    const int E = in_sizes[1] / 2;
    const int G = out_size;
    const int NL = in_sizes[11] / (128 * 128);  // 4

    char* ws = (char*)d_ws;
    size_t HS = (size_t)N * 128 * sizeof(unsigned short);      // bf16 feature plane
    unsigned short* h   = (unsigned short*)(ws);
    unsigned short* sum = (unsigned short*)(ws + HS);
    unsigned short* tmp = (unsigned short*)(ws + 2 * HS);
    char* p = ws + 3 * HS;
    float* sum2 = (float*)p;          p += (((size_t)N * 2 * 4 + 15) / 16) * 16;
    unsigned short* Wp = (unsigned short*)p; p += ((9 * 16384 * 2 + 15) / 16) * 16;
    int* deg = (int*)p;    p += (((size_t)N * 4 + 15) / 16) * 16;
    int* cur = (int*)p;    p += (((size_t)N * 4 + 15) / 16) * 16;
    int* rowptr = (int*)p; p += (((size_t)(N + 1) * 4 + 15) / 16) * 16;
    int* bsum = (int*)p;   p += 1024;
    int* col = (int*)p;

    const int* srcI = ei;
    const int* dstI = ei + E;

    const int NB = (N + 255) / 256;
    const int EB = (E + 255) / 256;
    const int GB = (N + 63) / 64;

    // CSR build
    (void)hipMemsetAsync(deg, 0, (size_t)N * 4, stream);
    deg_count<<<EB, 256, 0, stream>>>(dstI, deg, E);
    block_sum<<<NB, 256, 0, stream>>>(deg, bsum, N);
    scan_bsum<<<1, 256, 0, stream>>>(bsum, NB);
    make_rowptr<<<NB, 256, 0, stream>>>(deg, bsum, rowptr, cur, N);
    fill_col<<<EB, 256, 0, stream>>>(srcI, dstI, cur, col, E);

    // weight packing: slot 0 = conv1_W2, slots 1..NL = convs_W1, slots 1+NL.. = convs_W2
    pack_W<<<64, 256, 0, stream>>>(c1W2, Wp);
    for (int i = 0; i < NL; ++i) {
        pack_W<<<64, 256, 0, stream>>>(csW1 + (size_t)i * 16384, Wp + (size_t)(1 + i) * 16384);
        pack_W<<<64, 256, 0, stream>>>(csW2 + (size_t)i * 16384, Wp + (size_t)(1 + NL + i) * 16384);
    }

    // layer 1 (input dim 2)
    agg2<<<NB, 256, 0, stream>>>(x, rowptr, col, sum2, N);
    mlp1a<<<(N * 128 + 255) / 256, 256, 0, stream>>>(sum2, c1W1, c1b1, tmp, N);
    gemm_mfma<<<GB, 256, 0, stream>>>(tmp, Wp, c1b2, c1g, c1be, c1m, c1v, h, N);

    // layers 2..5
    for (int i = 0; i < NL; ++i) {
        aggH_bf16<<<(N + 3) / 4, 256, 0, stream>>>((const unsigned*)h, rowptr, col,
                                                   (unsigned*)sum, N);
        gemm_mfma<<<GB, 256, 0, stream>>>(sum, Wp + (size_t)(1 + i) * 16384, csb1 + i * 128,
                                          nullptr, nullptr, nullptr, nullptr, tmp, N);
        gemm_mfma<<<GB, 256, 0, stream>>>(tmp, Wp + (size_t)(1 + NL + i) * 16384, csb2 + i * 128,
                                          csg + i * 128, csbe + i * 128, csm + i * 128,
                                          csv + i * 128, h, N);
    }

    pool_head<<<G, 128, 0, stream>>>(h, batch, lin1W, lin1b, lin2W, lin2b, (float*)d_out, N);
}

// Round 4
// 557.970 us; speedup vs baseline: 1.5658x; 1.2737x over previous
//
#include <hip/hip_runtime.h>

// ---------------------------------------------------------------------------
// GIN inference, round 3:
//  - aggregation: 4 nodes/wave, 16 lanes x uint4 per row, 4x unrolled gathers
//    (fixes the MLP/latency bound seen in R2: VGPR=8, 1.2 TB/s)
//  - GEMM: 32 rows/wave (2 A-frag sets per B-frag load), 128-row blocks
//  - single pack_W launch for all 9 weight matrices
// ---------------------------------------------------------------------------

typedef __attribute__((ext_vector_type(8))) short short8;   // 8 bf16 (4 VGPRs)
typedef __attribute__((ext_vector_type(4))) float floatx4;  // 4 fp32 acc

__device__ __forceinline__ unsigned short f2bf(float f) {
    unsigned u = __float_as_uint(f);
    unsigned r = (u + 0x7fffu + ((u >> 16) & 1u)) >> 16;   // RNE
    return (unsigned short)r;
}
__device__ __forceinline__ float bf2f(unsigned short b) {
    return __uint_as_float(((unsigned)b) << 16);
}
__device__ __forceinline__ float bflo(unsigned u) { return __uint_as_float(u << 16); }
__device__ __forceinline__ float bfhi(unsigned u) { return __uint_as_float(u & 0xffff0000u); }

// ---------------- CSR build ----------------

__global__ void deg_count(const int* __restrict__ dst, int* __restrict__ deg, int E) {
    int e = blockIdx.x * 256 + threadIdx.x;
    if (e < E) atomicAdd(&deg[dst[e]], 1);
}

__global__ void block_sum(const int* __restrict__ deg, int* __restrict__ bsum, int N) {
    __shared__ int s[256];
    int tid = threadIdx.x;
    int i = blockIdx.x * 256 + tid;
    s[tid] = (i < N) ? deg[i] : 0;
    __syncthreads();
    for (int off = 128; off > 0; off >>= 1) {
        if (tid < off) s[tid] += s[tid + off];
        __syncthreads();
    }
    if (tid == 0) bsum[blockIdx.x] = s[0];
}

__global__ void scan_bsum(int* bsum, int NB) {
    __shared__ int s[256];
    int tid = threadIdx.x;
    int v = (tid < NB) ? bsum[tid] : 0;
    s[tid] = v;
    __syncthreads();
    for (int off = 1; off < 256; off <<= 1) {
        int t = (tid >= off) ? s[tid - off] : 0;
        __syncthreads();
        s[tid] += t;
        __syncthreads();
    }
    if (tid < NB) bsum[tid] = s[tid] - v;   // exclusive
}

__global__ void make_rowptr(const int* __restrict__ deg, const int* __restrict__ boff,
                            int* __restrict__ rowptr, int* __restrict__ cur, int N) {
    __shared__ int s[256];
    int tid = threadIdx.x;
    int i = blockIdx.x * 256 + tid;
    int v = (i < N) ? deg[i] : 0;
    s[tid] = v;
    __syncthreads();
    for (int off = 1; off < 256; off <<= 1) {
        int t = (tid >= off) ? s[tid - off] : 0;
        __syncthreads();
        s[tid] += t;
        __syncthreads();
    }
    int excl = s[tid] - v;
    int off0 = boff[blockIdx.x];
    if (i < N) {
        rowptr[i] = off0 + excl;
        cur[i]    = off0 + excl;
    }
    if (i == N - 1) rowptr[N] = off0 + s[tid];
}

__global__ void fill_col(const int* __restrict__ src, const int* __restrict__ dst,
                         int* __restrict__ cur, int* __restrict__ col, int E) {
    int e = blockIdx.x * 256 + threadIdx.x;
    if (e < E) {
        int p = atomicAdd(&cur[dst[e]], 1);
        col[p] = src[e];
    }
}

// ---------------- weight packing: all 9 matrices, one launch ----------------
// Wp[slot][((ks*8 + nt)*64 + lane)*8 + j] = bf16(W[ks*32 + (lane>>4)*8 + j][nt*16 + (lane&15)])

__global__ void pack_W_all(const float* __restrict__ c1W2, const float* __restrict__ csW1,
                           const float* __restrict__ csW2, unsigned short* __restrict__ Wp,
                           int NL) {
    int slot = blockIdx.x >> 6;
    int r = (blockIdx.x & 63) * 256 + threadIdx.x;   // 0..16383
    const float* W = (slot == 0) ? c1W2
                   : (slot <= NL ? csW1 + (size_t)(slot - 1) * 16384
                                 : csW2 + (size_t)(slot - 1 - NL) * 16384);
    int j = r & 7, lane = (r >> 3) & 63, nt = (r >> 9) & 7, ks = (r >> 12) & 3;
    int k = ks * 32 + (lane >> 4) * 8 + j;
    int n = nt * 16 + (lane & 15);
    Wp[(size_t)slot * 16384 + r] = f2bf(W[k * 128 + n]);
}

// ---------------- layer 1 (input dim = 2) ----------------

__global__ void agg2(const float* __restrict__ x, const int* __restrict__ rowptr,
                     const int* __restrict__ col, float* __restrict__ sum2, int N) {
    int n = blockIdx.x * 256 + threadIdx.x;
    if (n >= N) return;
    float ax = x[2 * n], ay = x[2 * n + 1];
    int e0 = rowptr[n], e1 = rowptr[n + 1];
    for (int j = e0; j < e1; ++j) {
        int s = col[j];
        ax += x[2 * s];
        ay += x[2 * s + 1];
    }
    sum2[2 * n] = ax;
    sum2[2 * n + 1] = ay;
}

__global__ void mlp1a(const float* __restrict__ sum2, const float* __restrict__ W1,
                      const float* __restrict__ b1, unsigned short* __restrict__ out, int N) {
    int idx = blockIdx.x * 256 + threadIdx.x;
    if (idx >= N * 128) return;
    int n = idx >> 7, c = idx & 127;
    float v = fmaf(sum2[2 * n], W1[c], fmaf(sum2[2 * n + 1], W1[128 + c], b1[c]));
    out[idx] = f2bf(fmaxf(v, 0.f));
}

// ---------------- aggregation: 4 nodes per wave, uint4 per lane -------------
// Row = 128 bf16 = 256 B = 16 lanes x 16 B. 4x unrolled independent gathers.

__device__ __forceinline__ void addrow(float* acc, uint4 v) {
    acc[0] += bflo(v.x); acc[1] += bfhi(v.x);
    acc[2] += bflo(v.y); acc[3] += bfhi(v.y);
    acc[4] += bflo(v.z); acc[5] += bfhi(v.z);
    acc[6] += bflo(v.w); acc[7] += bfhi(v.w);
}

__global__ void aggH_bf16(const uint4* __restrict__ h4, const int* __restrict__ rowptr,
                          const int* __restrict__ col, uint4* __restrict__ out4, int N) {
    int wave = (blockIdx.x * blockDim.x + threadIdx.x) >> 6;
    int lane = threadIdx.x & 63;
    int sub = lane >> 4, sl = lane & 15;
    int n = wave * 4 + sub;
    if (n >= N) return;
    size_t base = (size_t)n * 16 + sl;
    uint4 self = h4[base];
    float acc[8];
    acc[0] = bflo(self.x); acc[1] = bfhi(self.x);
    acc[2] = bflo(self.y); acc[3] = bfhi(self.y);
    acc[4] = bflo(self.z); acc[5] = bfhi(self.z);
    acc[6] = bflo(self.w); acc[7] = bfhi(self.w);
    int e0 = rowptr[n], e1 = rowptr[n + 1];
    int j = e0;
    for (; j + 4 <= e1; j += 4) {
        int s0 = col[j], s1 = col[j + 1], s2 = col[j + 2], s3 = col[j + 3];
        uint4 v0 = h4[(size_t)s0 * 16 + sl];
        uint4 v1 = h4[(size_t)s1 * 16 + sl];
        uint4 v2 = h4[(size_t)s2 * 16 + sl];
        uint4 v3 = h4[(size_t)s3 * 16 + sl];
        addrow(acc, v0);
        addrow(acc, v1);
        addrow(acc, v2);
        addrow(acc, v3);
    }
    for (; j < e1; ++j) {
        uint4 v = h4[(size_t)col[j] * 16 + sl];
        addrow(acc, v);
    }
    uint4 o;
    o.x = (unsigned)f2bf(acc[0]) | ((unsigned)f2bf(acc[1]) << 16);
    o.y = (unsigned)f2bf(acc[2]) | ((unsigned)f2bf(acc[3]) << 16);
    o.z = (unsigned)f2bf(acc[4]) | ((unsigned)f2bf(acc[5]) << 16);
    o.w = (unsigned)f2bf(acc[6]) | ((unsigned)f2bf(acc[7]) << 16);
    out4[base] = o;
}

// ---------------- [N,128] @ [128,128] bf16 MFMA + bias + relu (+BN) ---------
// 4 waves/block, 32 rows/wave (2 A-frag sets share every B-frag load).
// A-frag: lane holds A[rowset + (lane&15)][ks*32 + (lane>>4)*8 + j], j=0..7.
// C/D: col=lane&15, row=(lane>>4)*4+reg.

__launch_bounds__(256)
__global__ void gemm_mfma(const unsigned short* __restrict__ A,
                          const unsigned short* __restrict__ Wp,
                          const float* __restrict__ bias,
                          const float* __restrict__ gamma, const float* __restrict__ beta,
                          const float* __restrict__ mean, const float* __restrict__ var,
                          unsigned short* __restrict__ out, int N) {
    int wave = threadIdx.x >> 6, lane = threadIdx.x & 63;
    int row0 = blockIdx.x * 128 + wave * 32;
    if (row0 >= N) return;
    int m = lane & 15, q = lane >> 4;
    int ra = row0 + m;      if (ra > N - 1) ra = N - 1;   // clamp, masked at store
    int rb = row0 + 16 + m; if (rb > N - 1) rb = N - 1;

    short8 a0[4], a1[4];
#pragma unroll
    for (int ks = 0; ks < 4; ++ks) {
        a0[ks] = *(const short8*)&A[(size_t)ra * 128 + ks * 32 + q * 8];
        a1[ks] = *(const short8*)&A[(size_t)rb * 128 + ks * 32 + q * 8];
    }

    floatx4 acc0[8], acc1[8];
#pragma unroll
    for (int nt = 0; nt < 8; ++nt) {
        acc0[nt] = (floatx4){0.f, 0.f, 0.f, 0.f};
        acc1[nt] = (floatx4){0.f, 0.f, 0.f, 0.f};
    }

#pragma unroll
    for (int nt = 0; nt < 8; ++nt) {
        short8 b0 = *(const short8*)&Wp[((0 * 8 + nt) * 64 + lane) * 8];
        short8 b1 = *(const short8*)&Wp[((1 * 8 + nt) * 64 + lane) * 8];
        short8 b2 = *(const short8*)&Wp[((2 * 8 + nt) * 64 + lane) * 8];
        short8 b3 = *(const short8*)&Wp[((3 * 8 + nt) * 64 + lane) * 8];
        acc0[nt] = __builtin_amdgcn_mfma_f32_16x16x32_bf16(a0[0], b0, acc0[nt], 0, 0, 0);
        acc1[nt] = __builtin_amdgcn_mfma_f32_16x16x32_bf16(a1[0], b0, acc1[nt], 0, 0, 0);
        acc0[nt] = __builtin_amdgcn_mfma_f32_16x16x32_bf16(a0[1], b1, acc0[nt], 0, 0, 0);
        acc1[nt] = __builtin_amdgcn_mfma_f32_16x16x32_bf16(a1[1], b1, acc1[nt], 0, 0, 0);
        acc0[nt] = __builtin_amdgcn_mfma_f32_16x16x32_bf16(a0[2], b2, acc0[nt], 0, 0, 0);
        acc1[nt] = __builtin_amdgcn_mfma_f32_16x16x32_bf16(a1[2], b2, acc1[nt], 0, 0, 0);
        acc0[nt] = __builtin_amdgcn_mfma_f32_16x16x32_bf16(a0[3], b3, acc0[nt], 0, 0, 0);
        acc1[nt] = __builtin_amdgcn_mfma_f32_16x16x32_bf16(a1[3], b3, acc1[nt], 0, 0, 0);
    }

    bool bn = (gamma != nullptr);
#pragma unroll
    for (int nt = 0; nt < 8; ++nt) {
        int colc = nt * 16 + m;
        float bi = bias[colc];
        float scl = 1.f, shf = 0.f;
        if (bn) {
            float g = gamma[colc], be = beta[colc], me = mean[colc], va = var[colc];
            scl = g * rsqrtf(va + 1e-5f);
            shf = be - me * scl;
        }
#pragma unroll
        for (int rg = 0; rg < 4; ++rg) {
            int r_0 = row0 + q * 4 + rg;
            if (r_0 < N) {
                float v = fmaxf(acc0[nt][rg] + bi, 0.f);
                v = fmaf(v, scl, shf);
                out[(size_t)r_0 * 128 + colc] = f2bf(v);
            }
            int r_1 = row0 + 16 + q * 4 + rg;
            if (r_1 < N) {
                float v = fmaxf(acc1[nt][rg] + bi, 0.f);
                v = fmaf(v, scl, shf);
                out[(size_t)r_1 * 128 + colc] = f2bf(v);
            }
        }
    }
}

// ---------------- pooling (sorted batch) + MLP head, one block per graph ----

__global__ void pool_head(const unsigned short* __restrict__ h, const int* __restrict__ batch,
                          const float* __restrict__ lin1W, const float* __restrict__ lin1b,
                          const float* __restrict__ lin2W, const float* __restrict__ lin2b,
                          float* __restrict__ out, int N) {
    int g = blockIdx.x;
    int c = threadIdx.x;  // 0..127
    int lo = 0, hi = N;
    while (lo < hi) { int mm = (lo + hi) >> 1; if (batch[mm] < g) lo = mm + 1; else hi = mm; }
    int start = lo;
    lo = start; hi = N;
    while (lo < hi) { int mm = (lo + hi) >> 1; if (batch[mm] < g + 1) lo = mm + 1; else hi = mm; }
    int end = lo;

    float acc = 0.f;
    for (int n = start; n < end; ++n) acc += bf2f(h[(size_t)n * 128 + c]);

    __shared__ float pl[128];
    pl[c] = acc;
    __syncthreads();

    float o = lin1b[c];
    for (int k = 0; k < 128; ++k) o = fmaf(pl[k], lin1W[k * 128 + c], o);
    o = fmaxf(o, 0.f) * lin2W[c];

    __shared__ float red[128];
    red[c] = o;
    __syncthreads();
    for (int off = 64; off > 0; off >>= 1) {
        if (c < off) red[c] += red[c + off];
        __syncthreads();
    }
    if (c == 0) out[g] = red[0] + lin2b[0];
}

// ---------------------------------------------------------------------------

extern "C" void kernel_launch(void* const* d_in, const int* in_sizes, int n_in,
                              void* d_out, int out_size, void* d_ws, size_t ws_size,
                              hipStream_t stream) {
    const float* x     = (const float*)d_in[0];
    const int*   ei    = (const int*)d_in[1];
    const int*   batch = (const int*)d_in[2];
    const float* c1W1  = (const float*)d_in[3];
    const float* c1b1  = (const float*)d_in[4];
    const float* c1W2  = (const float*)d_in[5];
    const float* c1b2  = (const float*)d_in[6];
    const float* c1g   = (const float*)d_in[7];
    const float* c1be  = (const float*)d_in[8];
    const float* c1m   = (const float*)d_in[9];
    const float* c1v   = (const float*)d_in[10];
    const float* csW1  = (const float*)d_in[11];
    const float* csb1  = (const float*)d_in[12];
    const float* csW2  = (const float*)d_in[13];
    const float* csb2  = (const float*)d_in[14];
    const float* csg   = (const float*)d_in[15];
    const float* csbe  = (const float*)d_in[16];
    const float* csm   = (const float*)d_in[17];
    const float* csv   = (const float*)d_in[18];
    const float* lin1W = (const float*)d_in[19];
    const float* lin1b = (const float*)d_in[20];
    const float* lin2W = (const float*)d_in[21];
    const float* lin2b = (const float*)d_in[22];

    const int N = in_sizes[0] / 2;
    const int E = in_sizes[1] / 2;
    const int G = out_size;
    const int NL = in_sizes[11] / (128 * 128);  // 4

    char* ws = (char*)d_ws;
    size_t HS = (size_t)N * 128 * sizeof(unsigned short);      // bf16 feature plane
    unsigned short* h   = (unsigned short*)(ws);
    unsigned short* sum = (unsigned short*)(ws + HS);
    unsigned short* tmp = (unsigned short*)(ws + 2 * HS);
    char* p = ws + 3 * HS;
    float* sum2 = (float*)p;          p += (((size_t)N * 2 * 4 + 15) / 16) * 16;
    unsigned short* Wp = (unsigned short*)p; p += ((9 * 16384 * 2 + 15) / 16) * 16;
    int* deg = (int*)p;    p += (((size_t)N * 4 + 15) / 16) * 16;
    int* cur = (int*)p;    p += (((size_t)N * 4 + 15) / 16) * 16;
    int* rowptr = (int*)p; p += (((size_t)(N + 1) * 4 + 15) / 16) * 16;
    int* bsum = (int*)p;   p += 1024;
    int* col = (int*)p;

    const int* srcI = ei;
    const int* dstI = ei + E;

    const int NB = (N + 255) / 256;
    const int EB = (E + 255) / 256;

    // CSR build
    (void)hipMemsetAsync(deg, 0, (size_t)N * 4, stream);
    deg_count<<<EB, 256, 0, stream>>>(dstI, deg, E);
    block_sum<<<NB, 256, 0, stream>>>(deg, bsum, N);
    scan_bsum<<<1, 256, 0, stream>>>(bsum, NB);
    make_rowptr<<<NB, 256, 0, stream>>>(deg, bsum, rowptr, cur, N);
    fill_col<<<EB, 256, 0, stream>>>(srcI, dstI, cur, col, E);

    // weight packing: slot 0 = conv1_W2, slots 1..NL = convs_W1, slots 1+NL.. = convs_W2
    pack_W_all<<<(1 + 2 * NL) * 64, 256, 0, stream>>>(c1W2, csW1, csW2, Wp, NL);

    const int GEMMB = (N + 127) / 128;
    const int AGGB = ((N + 3) / 4 + 3) / 4;   // waves = ceil(N/4), blocks = ceil(waves/4)

    // layer 1 (input dim 2)
    agg2<<<NB, 256, 0, stream>>>(x, rowptr, col, sum2, N);
    mlp1a<<<(N * 128 + 255) / 256, 256, 0, stream>>>(sum2, c1W1, c1b1, tmp, N);
    gemm_mfma<<<GEMMB, 256, 0, stream>>>(tmp, Wp, c1b2, c1g, c1be, c1m, c1v, h, N);

    // layers 2..5
    for (int i = 0; i < NL; ++i) {
        aggH_bf16<<<AGGB, 256, 0, stream>>>((const uint4*)h, rowptr, col, (uint4*)sum, N);
        gemm_mfma<<<GEMMB, 256, 0, stream>>>(sum, Wp + (size_t)(1 + i) * 16384, csb1 + i * 128,
                                             nullptr, nullptr, nullptr, nullptr, tmp, N);
        gemm_mfma<<<GEMMB, 256, 0, stream>>>(tmp, Wp + (size_t)(1 + NL + i) * 16384, csb2 + i * 128,
                                             csg + i * 128, csbe + i * 128, csm + i * 128,
                                             csv + i * 128, h, N);
    }

    pool_head<<<G, 128, 0, stream>>>(h, batch, lin1W, lin1b, lin2W, lin2b, (float*)d_out, N);
}

// Round 5
// 421.061 us; speedup vs baseline: 2.0750x; 1.3252x over previous
//
#include <hip/hip_runtime.h>

// ---------------------------------------------------------------------------
// GIN inference, round 4:
//  - bucketed CSR build (no scattered global writes, no global atom-scatter)
//  - permuted feature layout pi(p) = (p&7)*16 + (p>>3)  -> b128 GEMM epilogues
//  - fused MLP kernel per layer: W1+relu -> wave-private LDS -> W2+relu+BN
// ---------------------------------------------------------------------------

typedef __attribute__((ext_vector_type(8))) short short8;   // 8 bf16 (4 VGPRs)
typedef __attribute__((ext_vector_type(4))) float floatx4;  // 4 fp32 acc

__device__ __forceinline__ unsigned f2bf(float f) {
    unsigned u = __float_as_uint(f);
    return (u + 0x7fffu + ((u >> 16) & 1u)) >> 16;   // RNE
}
__device__ __forceinline__ float bf2f(unsigned short b) {
    return __uint_as_float(((unsigned)b) << 16);
}
__device__ __forceinline__ float bflo(unsigned u) { return __uint_as_float(u << 16); }
__device__ __forceinline__ float bfhi(unsigned u) { return __uint_as_float(u & 0xffff0000u); }

__device__ __forceinline__ uint4 pack8bf(const float* v) {
    uint4 o;
    o.x = f2bf(v[0]) | (f2bf(v[1]) << 16);
    o.y = f2bf(v[2]) | (f2bf(v[3]) << 16);
    o.z = f2bf(v[4]) | (f2bf(v[5]) << 16);
    o.w = f2bf(v[6]) | (f2bf(v[7]) << 16);
    return o;
}

// ======================= bucketed CSR build =======================
// buckets of 128 nodes: b = dst >> 7. nb = ceil(N/128) <= 512.

__global__ void bucket_hist(const int* __restrict__ dstA, int* __restrict__ bcnt,
                            int E, int nb) {
    __shared__ int hist[512];
    int tid = threadIdx.x;
    int start = blockIdx.x * 4096;
    for (int i = tid; i < 512; i += 256) hist[i] = 0;
    __syncthreads();
#pragma unroll
    for (int t = 0; t < 16; ++t) {
        int e = start + t * 256 + tid;
        if (e < E) atomicAdd(&hist[dstA[e] >> 7], 1);
    }
    __syncthreads();
    for (int i = tid; i < nb; i += 256)
        if (hist[i]) atomicAdd(&bcnt[i], hist[i]);
}

// single block, 512 threads: exclusive scan of bcnt -> boff[0..nb], copy to bcur
__global__ void scan_buckets(const int* __restrict__ bcnt, int* __restrict__ boff,
                             int* __restrict__ bcur, int* __restrict__ rowptr,
                             int nb, int N) {
    __shared__ int sa[512], sb[512];
    int t = threadIdx.x;
    sa[t] = (t < nb) ? bcnt[t] : 0;
    __syncthreads();
    int* ps = sa;
    int* pd = sb;
    for (int o = 1; o < 512; o <<= 1) {
        pd[t] = ps[t] + ((t >= o) ? ps[t - o] : 0);
        __syncthreads();
        int* tmp = ps; ps = pd; pd = tmp;
    }
    // ps = inclusive scan
    if (t <= nb) boff[t] = (t == 0) ? 0 : ps[t - 1];
    if (t < nb) bcur[t] = (t == 0) ? 0 : ps[t - 1];
    if (t == 0) rowptr[N] = ps[nb - 1];
}

// tile of 4096 edges: LDS-reorder by bucket, then coalesced runs to staging.
// staged value packs (src << 7) | (dst & 127).
__global__ void bucket_scatter(const int* __restrict__ srcA, const int* __restrict__ dstA,
                               int* __restrict__ bcur, unsigned* __restrict__ staging,
                               int E, int nb) {
    __shared__ int hist[512];
    __shared__ int sa[512], sb[512];
    __shared__ int toff[513];
    __shared__ int gbase[512];
    __shared__ unsigned pk[4096];
    int tid = threadIdx.x;
    int start = blockIdx.x * 4096;
    for (int i = tid; i < 512; i += 256) hist[i] = 0;
    __syncthreads();
    int bidx[16], rank[16];
    unsigned pval[16];
#pragma unroll
    for (int t = 0; t < 16; ++t) {
        int e = start + t * 256 + tid;
        bidx[t] = -1;
        if (e < E) {
            int d = dstA[e];
            int s = srcA[e];
            int b = d >> 7;
            bidx[t] = b;
            rank[t] = atomicAdd(&hist[b], 1);
            pval[t] = ((unsigned)s << 7) | (unsigned)(d & 127);
        }
    }
    __syncthreads();
    // inclusive scan of hist (512) with 256 threads, 2 elems each, ping-pong
    sa[tid] = hist[tid];
    sa[tid + 256] = hist[tid + 256];
    __syncthreads();
    int* ps = sa;
    int* pd = sb;
    for (int o = 1; o < 512; o <<= 1) {
        pd[tid] = ps[tid] + ((tid >= o) ? ps[tid - o] : 0);
        int j2 = tid + 256;
        pd[j2] = ps[j2] + ((j2 >= o) ? ps[j2 - o] : 0);
        __syncthreads();
        int* tmp = ps; ps = pd; pd = tmp;
    }
    toff[tid + 1] = ps[tid];
    toff[tid + 257] = ps[tid + 256];
    if (tid == 0) toff[0] = 0;
    __syncthreads();
    // reserve global space per bucket
    for (int b = tid; b < nb; b += 256) {
        int c = hist[b];
        gbase[b] = c ? atomicAdd(&bcur[b], c) : 0;
    }
    // place into LDS in bucket-sorted order
#pragma unroll
    for (int t = 0; t < 16; ++t)
        if (bidx[t] >= 0) pk[toff[bidx[t]] + rank[t]] = pval[t];
    __syncthreads();
    // coalesced flush; binary-search the bucket of each LDS slot
    int total = toff[512];
    for (int i = tid; i < total; i += 256) {
        int lo = 0, hi = 512;
        while (hi - lo > 1) {
            int mid = (lo + hi) >> 1;
            if (toff[mid] <= i) lo = mid; else hi = mid;
        }
        staging[gbase[lo] + (i - toff[lo])] = pk[i];
    }
}

// one block per bucket: build rowptr slice + col slice entirely in LDS.
__global__ void bucket_build(const unsigned* __restrict__ staging, const int* __restrict__ boff,
                             int* __restrict__ rowptr, int* __restrict__ col, int N) {
    __shared__ int deg[128], sca[128], scb[128], curL[128];
    __shared__ unsigned pk[4096];
    __shared__ int colL[4096];
    int b = blockIdx.x, tid = threadIdx.x;
    int lo = boff[b], hi = boff[b + 1];
    int cnt = hi - lo;
    if (cnt > 4096) cnt = 4096;
    for (int i = tid; i < cnt; i += 256) pk[i] = staging[lo + i];
    if (tid < 128) deg[tid] = 0;
    __syncthreads();
    for (int i = tid; i < cnt; i += 256) atomicAdd(&deg[pk[i] & 127u], 1);
    __syncthreads();
    if (tid < 128) sca[tid] = deg[tid];
    __syncthreads();
    int* ps = sca;
    int* pd = scb;
    for (int o = 1; o < 128; o <<= 1) {
        if (tid < 128) pd[tid] = ps[tid] + ((tid >= o) ? ps[tid - o] : 0);
        __syncthreads();
        int* tmp = ps; ps = pd; pd = tmp;
    }
    if (tid < 128) {
        int excl = tid ? ps[tid - 1] : 0;
        curL[tid] = excl;
        int node = b * 128 + tid;
        if (node < N) rowptr[node] = lo + excl;
    }
    __syncthreads();
    for (int i = tid; i < cnt; i += 256) {
        unsigned v = pk[i];
        int p = atomicAdd(&curL[v & 127u], 1);
        colL[p] = (int)(v >> 7);
    }
    __syncthreads();
    for (int i = tid; i < cnt; i += 256) col[lo + i] = colL[i];
}

// ======================= weight packing (perm-aware) =======================
// k-slot u = ks*32 + q*8 + j holds ORIGINAL k-col pi(u) = (u&7)*16 + (u>>3).
// Wp[slot][((ks*8+nt)*64+lane)*8 + j] = bf16(W[pi(u)][nt*16 + (lane&15)])

__global__ void pack_W_all(const float* __restrict__ c1W2, const float* __restrict__ csW1,
                           const float* __restrict__ csW2, unsigned short* __restrict__ Wp,
                           int NL) {
    int slot = blockIdx.x >> 6;
    int r = (blockIdx.x & 63) * 256 + threadIdx.x;   // 0..16383
    const float* W = (slot == 0) ? c1W2
                   : (slot <= NL ? csW1 + (size_t)(slot - 1) * 16384
                                 : csW2 + (size_t)(slot - 1 - NL) * 16384);
    int j = r & 7, lane = (r >> 3) & 63, nt = (r >> 9) & 7, ks = (r >> 12) & 3;
    int u = ks * 32 + (lane >> 4) * 8 + j;
    int k = (u & 7) * 16 + (u >> 3);                 // pi(u)
    int n = nt * 16 + (lane & 15);
    Wp[(size_t)slot * 16384 + r] = (unsigned short)f2bf(W[k * 128 + n]);
}

// ======================= layer 1 (input dim = 2) =======================

__global__ void agg2(const float* __restrict__ x, const int* __restrict__ rowptr,
                     const int* __restrict__ col, float* __restrict__ sum2, int N) {
    int n = blockIdx.x * 256 + threadIdx.x;
    if (n >= N) return;
    const float2* x2 = (const float2*)x;
    float2 self = x2[n];
    float ax = self.x, ay = self.y;
    int e0 = rowptr[n], e1 = rowptr[n + 1];
    for (int j = e0; j < e1; ++j) {
        float2 v = x2[col[j]];
        ax += v.x;
        ay += v.y;
    }
    sum2[2 * n] = ax;
    sum2[2 * n + 1] = ay;
}

// writes tmp in permuted layout: position p holds orig col pi(p)
__global__ void mlp1a(const float* __restrict__ sum2, const float* __restrict__ W1,
                      const float* __restrict__ b1, unsigned short* __restrict__ out, int N) {
    int idx = blockIdx.x * 256 + threadIdx.x;
    if (idx >= N * 128) return;
    int n = idx >> 7, p = idx & 127;
    int c = (p & 7) * 16 + (p >> 3);
    float v = fmaf(sum2[2 * n], W1[c], fmaf(sum2[2 * n + 1], W1[128 + c], b1[c]));
    out[idx] = (unsigned short)f2bf(fmaxf(v, 0.f));
}

// ======================= aggregation (layout-agnostic) =======================

__device__ __forceinline__ void addrow(float* acc, uint4 v) {
    acc[0] += bflo(v.x); acc[1] += bfhi(v.x);
    acc[2] += bflo(v.y); acc[3] += bfhi(v.y);
    acc[4] += bflo(v.z); acc[5] += bfhi(v.z);
    acc[6] += bflo(v.w); acc[7] += bfhi(v.w);
}

__global__ void aggH_bf16(const uint4* __restrict__ h4, const int* __restrict__ rowptr,
                          const int* __restrict__ col, uint4* __restrict__ out4, int N) {
    int wave = (blockIdx.x * blockDim.x + threadIdx.x) >> 6;
    int lane = threadIdx.x & 63;
    int sub = lane >> 4, sl = lane & 15;
    int n = wave * 4 + sub;
    if (n >= N) return;
    size_t base = (size_t)n * 16 + sl;
    uint4 self = h4[base];
    float acc[8];
    acc[0] = bflo(self.x); acc[1] = bfhi(self.x);
    acc[2] = bflo(self.y); acc[3] = bfhi(self.y);
    acc[4] = bflo(self.z); acc[5] = bfhi(self.z);
    acc[6] = bflo(self.w); acc[7] = bfhi(self.w);
    int e0 = rowptr[n], e1 = rowptr[n + 1];
    int j = e0;
    for (; j + 4 <= e1; j += 4) {
        int s0 = col[j], s1 = col[j + 1], s2 = col[j + 2], s3 = col[j + 3];
        uint4 v0 = h4[(size_t)s0 * 16 + sl];
        uint4 v1 = h4[(size_t)s1 * 16 + sl];
        uint4 v2 = h4[(size_t)s2 * 16 + sl];
        uint4 v3 = h4[(size_t)s3 * 16 + sl];
        addrow(acc, v0);
        addrow(acc, v1);
        addrow(acc, v2);
        addrow(acc, v3);
    }
    for (; j < e1; ++j) addrow(acc, h4[(size_t)col[j] * 16 + sl]);
    uint4 o;
    float lo4[4] = {acc[0], acc[2], acc[4], acc[6]};
    o.x = f2bf(acc[0]) | (f2bf(acc[1]) << 16);
    o.y = f2bf(acc[2]) | (f2bf(acc[3]) << 16);
    o.z = f2bf(acc[4]) | (f2bf(acc[5]) << 16);
    o.w = f2bf(acc[6]) | (f2bf(acc[7]) << 16);
    (void)lo4;
    out4[base] = o;
}

// ======================= fused GIN MLP =======================
// 4 waves/block, 32 rows/wave. Stage1: A@W1+b1,relu -> wave-private LDS.
// Stage2: LDS@W2+b2,relu,BN -> out (permuted layout, b128 stores).

__launch_bounds__(256)
__global__ void gin_mlp(const unsigned short* __restrict__ A,
                        const unsigned short* __restrict__ W1p, const float* __restrict__ b1,
                        const unsigned short* __restrict__ W2p, const float* __restrict__ b2,
                        const float* __restrict__ gamma, const float* __restrict__ beta,
                        const float* __restrict__ mean, const float* __restrict__ var,
                        unsigned short* __restrict__ out, int N) {
    __shared__ unsigned short hbuf[4][32][136];   // 272B row stride: <=2-way bank conflicts
    int wave = threadIdx.x >> 6, lane = threadIdx.x & 63;
    int row0 = blockIdx.x * 128 + wave * 32;
    if (row0 >= N) return;
    int m = lane & 15, q = lane >> 4;
    int ra = row0 + m;      if (ra > N - 1) ra = N - 1;
    int rb = row0 + 16 + m; if (rb > N - 1) rb = N - 1;

    short8 a0[4], a1[4];
#pragma unroll
    for (int ks = 0; ks < 4; ++ks) {
        a0[ks] = *(const short8*)&A[(size_t)ra * 128 + ks * 32 + q * 8];
        a1[ks] = *(const short8*)&A[(size_t)rb * 128 + ks * 32 + q * 8];
    }

    floatx4 c0[8], c1[8];
#pragma unroll
    for (int nt = 0; nt < 8; ++nt) {
        c0[nt] = (floatx4){0.f, 0.f, 0.f, 0.f};
        c1[nt] = (floatx4){0.f, 0.f, 0.f, 0.f};
    }
#pragma unroll
    for (int nt = 0; nt < 8; ++nt) {
        short8 w0 = *(const short8*)&W1p[((0 * 8 + nt) * 64 + lane) * 8];
        short8 w1 = *(const short8*)&W1p[((1 * 8 + nt) * 64 + lane) * 8];
        short8 w2 = *(const short8*)&W1p[((2 * 8 + nt) * 64 + lane) * 8];
        short8 w3 = *(const short8*)&W1p[((3 * 8 + nt) * 64 + lane) * 8];
        c0[nt] = __builtin_amdgcn_mfma_f32_16x16x32_bf16(a0[0], w0, c0[nt], 0, 0, 0);
        c1[nt] = __builtin_amdgcn_mfma_f32_16x16x32_bf16(a1[0], w0, c1[nt], 0, 0, 0);
        c0[nt] = __builtin_amdgcn_mfma_f32_16x16x32_bf16(a0[1], w1, c0[nt], 0, 0, 0);
        c1[nt] = __builtin_amdgcn_mfma_f32_16x16x32_bf16(a1[1], w1, c1[nt], 0, 0, 0);
        c0[nt] = __builtin_amdgcn_mfma_f32_16x16x32_bf16(a0[2], w2, c0[nt], 0, 0, 0);
        c1[nt] = __builtin_amdgcn_mfma_f32_16x16x32_bf16(a1[2], w2, c1[nt], 0, 0, 0);
        c0[nt] = __builtin_amdgcn_mfma_f32_16x16x32_bf16(a0[3], w3, c0[nt], 0, 0, 0);
        c1[nt] = __builtin_amdgcn_mfma_f32_16x16x32_bf16(a1[3], w3, c1[nt], 0, 0, 0);
    }

    // stage-1 epilogue -> LDS (wave-private, no barrier needed)
    float b1v[8];
#pragma unroll
    for (int nt = 0; nt < 8; ++nt) b1v[nt] = b1[nt * 16 + m];
#pragma unroll
    for (int rg = 0; rg < 4; ++rg) {
        float v0[8], v1[8];
#pragma unroll
        for (int nt = 0; nt < 8; ++nt) {
            v0[nt] = fmaxf(c0[nt][rg] + b1v[nt], 0.f);
            v1[nt] = fmaxf(c1[nt][rg] + b1v[nt], 0.f);
        }
        *(uint4*)&hbuf[wave][q * 4 + rg][m * 8] = pack8bf(v0);
        *(uint4*)&hbuf[wave][16 + q * 4 + rg][m * 8] = pack8bf(v1);
    }

    // stage-2 A-frags from LDS (k-slot u holds orig col pi(u) -> matches W2p pack)
    short8 d0[4], d1[4];
#pragma unroll
    for (int ks = 0; ks < 4; ++ks) {
        d0[ks] = *(const short8*)&hbuf[wave][m][ks * 32 + q * 8];
        d1[ks] = *(const short8*)&hbuf[wave][16 + m][ks * 32 + q * 8];
    }

    floatx4 e0[8], e1[8];
#pragma unroll
    for (int nt = 0; nt < 8; ++nt) {
        e0[nt] = (floatx4){0.f, 0.f, 0.f, 0.f};
        e1[nt] = (floatx4){0.f, 0.f, 0.f, 0.f};
    }
#pragma unroll
    for (int nt = 0; nt < 8; ++nt) {
        short8 w0 = *(const short8*)&W2p[((0 * 8 + nt) * 64 + lane) * 8];
        short8 w1 = *(const short8*)&W2p[((1 * 8 + nt) * 64 + lane) * 8];
        short8 w2 = *(const short8*)&W2p[((2 * 8 + nt) * 64 + lane) * 8];
        short8 w3 = *(const short8*)&W2p[((3 * 8 + nt) * 64 + lane) * 8];
        e0[nt] = __builtin_amdgcn_mfma_f32_16x16x32_bf16(d0[0], w0, e0[nt], 0, 0, 0);
        e1[nt] = __builtin_amdgcn_mfma_f32_16x16x32_bf16(d1[0], w0, e1[nt], 0, 0, 0);
        e0[nt] = __builtin_amdgcn_mfma_f32_16x16x32_bf16(d0[1], w1, e0[nt], 0, 0, 0);
        e1[nt] = __builtin_amdgcn_mfma_f32_16x16x32_bf16(d1[1], w1, e1[nt], 0, 0, 0);
        e0[nt] = __builtin_amdgcn_mfma_f32_16x16x32_bf16(d0[2], w2, e0[nt], 0, 0, 0);
        e1[nt] = __builtin_amdgcn_mfma_f32_16x16x32_bf16(d1[2], w2, e1[nt], 0, 0, 0);
        e0[nt] = __builtin_amdgcn_mfma_f32_16x16x32_bf16(d0[3], w3, e0[nt], 0, 0, 0);
        e1[nt] = __builtin_amdgcn_mfma_f32_16x16x32_bf16(d1[3], w3, e1[nt], 0, 0, 0);
    }

    // stage-2 epilogue: bias, relu, BN -> permuted b128 stores
    float b2v[8], scl[8], shf[8];
#pragma unroll
    for (int nt = 0; nt < 8; ++nt) {
        int c = nt * 16 + m;
        b2v[nt] = b2[c];
        float s = gamma[c] * rsqrtf(var[c] + 1e-5f);
        scl[nt] = s;
        shf[nt] = beta[c] - mean[c] * s;
    }
#pragma unroll
    for (int rg = 0; rg < 4; ++rg) {
        int r0 = row0 + q * 4 + rg;
        int r1 = row0 + 16 + q * 4 + rg;
        float v0[8], v1[8];
#pragma unroll
        for (int nt = 0; nt < 8; ++nt) {
            v0[nt] = fmaf(fmaxf(e0[nt][rg] + b2v[nt], 0.f), scl[nt], shf[nt]);
            v1[nt] = fmaf(fmaxf(e1[nt][rg] + b2v[nt], 0.f), scl[nt], shf[nt]);
        }
        if (r0 < N) *(uint4*)&out[(size_t)r0 * 128 + m * 8] = pack8bf(v0);
        if (r1 < N) *(uint4*)&out[(size_t)r1 * 128 + m * 8] = pack8bf(v1);
    }
}

// ======================= layer-1 single GEMM (W2 + bias + relu + BN) ========

__launch_bounds__(256)
__global__ void gemm_one(const unsigned short* __restrict__ A,
                         const unsigned short* __restrict__ Wp,
                         const float* __restrict__ bias,
                         const float* __restrict__ gamma, const float* __restrict__ beta,
                         const float* __restrict__ mean, const float* __restrict__ var,
                         unsigned short* __restrict__ out, int N) {
    int wave = threadIdx.x >> 6, lane = threadIdx.x & 63;
    int row0 = blockIdx.x * 128 + wave * 32;
    if (row0 >= N) return;
    int m = lane & 15, q = lane >> 4;
    int ra = row0 + m;      if (ra > N - 1) ra = N - 1;
    int rb = row0 + 16 + m; if (rb > N - 1) rb = N - 1;

    short8 a0[4], a1[4];
#pragma unroll
    for (int ks = 0; ks < 4; ++ks) {
        a0[ks] = *(const short8*)&A[(size_t)ra * 128 + ks * 32 + q * 8];
        a1[ks] = *(const short8*)&A[(size_t)rb * 128 + ks * 32 + q * 8];
    }
    floatx4 c0[8], c1[8];
#pragma unroll
    for (int nt = 0; nt < 8; ++nt) {
        c0[nt] = (floatx4){0.f, 0.f, 0.f, 0.f};
        c1[nt] = (floatx4){0.f, 0.f, 0.f, 0.f};
    }
#pragma unroll
    for (int nt = 0; nt < 8; ++nt) {
        short8 w0 = *(const short8*)&Wp[((0 * 8 + nt) * 64 + lane) * 8];
        short8 w1 = *(const short8*)&Wp[((1 * 8 + nt) * 64 + lane) * 8];
        short8 w2 = *(const short8*)&Wp[((2 * 8 + nt) * 64 + lane) * 8];
        short8 w3 = *(const short8*)&Wp[((3 * 8 + nt) * 64 + lane) * 8];
        c0[nt] = __builtin_amdgcn_mfma_f32_16x16x32_bf16(a0[0], w0, c0[nt], 0, 0, 0);
        c1[nt] = __builtin_amdgcn_mfma_f32_16x16x32_bf16(a1[0], w0, c1[nt], 0, 0, 0);
        c0[nt] = __builtin_amdgcn_mfma_f32_16x16x32_bf16(a0[1], w1, c0[nt], 0, 0, 0);
        c1[nt] = __builtin_amdgcn_mfma_f32_16x16x32_bf16(a1[1], w1, c1[nt], 0, 0, 0);
        c0[nt] = __builtin_amdgcn_mfma_f32_16x16x32_bf16(a0[2], w2, c0[nt], 0, 0, 0);
        c1[nt] = __builtin_amdgcn_mfma_f32_16x16x32_bf16(a1[2], w2, c1[nt], 0, 0, 0);
        c0[nt] = __builtin_amdgcn_mfma_f32_16x16x32_bf16(a0[3], w3, c0[nt], 0, 0, 0);
        c1[nt] = __builtin_amdgcn_mfma_f32_16x16x32_bf16(a1[3], w3, c1[nt], 0, 0, 0);
    }
    float bv[8], scl[8], shf[8];
#pragma unroll
    for (int nt = 0; nt < 8; ++nt) {
        int c = nt * 16 + m;
        bv[nt] = bias[c];
        float s = gamma[c] * rsqrtf(var[c] + 1e-5f);
        scl[nt] = s;
        shf[nt] = beta[c] - mean[c] * s;
    }
#pragma unroll
    for (int rg = 0; rg < 4; ++rg) {
        int r0 = row0 + q * 4 + rg;
        int r1 = row0 + 16 + q * 4 + rg;
        float v0[8], v1[8];
#pragma unroll
        for (int nt = 0; nt < 8; ++nt) {
            v0[nt] = fmaf(fmaxf(c0[nt][rg] + bv[nt], 0.f), scl[nt], shf[nt]);
            v1[nt] = fmaf(fmaxf(c1[nt][rg] + bv[nt], 0.f), scl[nt], shf[nt]);
        }
        if (r0 < N) *(uint4*)&out[(size_t)r0 * 128 + m * 8] = pack8bf(v0);
        if (r1 < N) *(uint4*)&out[(size_t)r1 * 128 + m * 8] = pack8bf(v1);
    }
}

// ======================= pooling + head =======================

__global__ void pool_head(const unsigned short* __restrict__ h, const int* __restrict__ batch,
                          const float* __restrict__ lin1W, const float* __restrict__ lin1b,
                          const float* __restrict__ lin2W, const float* __restrict__ lin2b,
                          float* __restrict__ out, int N) {
    int g = blockIdx.x;
    int c = threadIdx.x;  // 0..127 (c = permuted position for h reads, orig col for lin1 out)
    int lo = 0, hi = N;
    while (lo < hi) { int mm = (lo + hi) >> 1; if (batch[mm] < g) lo = mm + 1; else hi = mm; }
    int start = lo;
    lo = start; hi = N;
    while (lo < hi) { int mm = (lo + hi) >> 1; if (batch[mm] < g + 1) lo = mm + 1; else hi = mm; }
    int end = lo;

    float acc = 0.f;
    for (int n = start; n < end; ++n) acc += bf2f(h[(size_t)n * 128 + c]);

    __shared__ float pl[128];
    pl[c] = acc;
    __syncthreads();

    float o = lin1b[c];
    for (int k = 0; k < 128; ++k) {
        int ko = (k & 7) * 16 + (k >> 3);   // orig col held at permuted position k
        o = fmaf(pl[k], lin1W[ko * 128 + c], o);
    }
    o = fmaxf(o, 0.f) * lin2W[c];

    __shared__ float red[128];
    red[c] = o;
    __syncthreads();
    for (int off = 64; off > 0; off >>= 1) {
        if (c < off) red[c] += red[c + off];
        __syncthreads();
    }
    if (c == 0) out[g] = red[0] + lin2b[0];
}

// ---------------------------------------------------------------------------

extern "C" void kernel_launch(void* const* d_in, const int* in_sizes, int n_in,
                              void* d_out, int out_size, void* d_ws, size_t ws_size,
                              hipStream_t stream) {
    const float* x     = (const float*)d_in[0];
    const int*   ei    = (const int*)d_in[1];
    const int*   batch = (const int*)d_in[2];
    const float* c1W1  = (const float*)d_in[3];
    const float* c1b1  = (const float*)d_in[4];
    const float* c1W2  = (const float*)d_in[5];
    const float* c1b2  = (const float*)d_in[6];
    const float* c1g   = (const float*)d_in[7];
    const float* c1be  = (const float*)d_in[8];
    const float* c1m   = (const float*)d_in[9];
    const float* c1v   = (const float*)d_in[10];
    const float* csW1  = (const float*)d_in[11];
    const float* csb1  = (const float*)d_in[12];
    const float* csW2  = (const float*)d_in[13];
    const float* csb2  = (const float*)d_in[14];
    const float* csg   = (const float*)d_in[15];
    const float* csbe  = (const float*)d_in[16];
    const float* csm   = (const float*)d_in[17];
    const float* csv   = (const float*)d_in[18];
    const float* lin1W = (const float*)d_in[19];
    const float* lin1b = (const float*)d_in[20];
    const float* lin2W = (const float*)d_in[21];
    const float* lin2b = (const float*)d_in[22];

    const int N = in_sizes[0] / 2;
    const int E = in_sizes[1] / 2;
    const int G = out_size;
    const int NL = in_sizes[11] / (128 * 128);  // 4
    const int nb = (N + 127) >> 7;              // buckets of 128 nodes

    char* ws = (char*)d_ws;
    size_t HS = (size_t)N * 128 * sizeof(unsigned short);      // bf16 feature plane
    unsigned short* h   = (unsigned short*)(ws);
    unsigned short* sum = (unsigned short*)(ws + HS);
    unsigned short* tmp = (unsigned short*)(ws + 2 * HS);
    char* p = ws + 3 * HS;
    float* sum2 = (float*)p;                 p += (((size_t)N * 2 * 4 + 15) / 16) * 16;
    unsigned short* Wp = (unsigned short*)p; p += ((9 * 16384 * 2 + 15) / 16) * 16;
    int* rowptr = (int*)p;                   p += (((size_t)(N + 1) * 4 + 15) / 16) * 16;
    int* col = (int*)p;                      p += (((size_t)E * 4 + 15) / 16) * 16;
    unsigned* staging = (unsigned*)p;        p += (((size_t)E * 4 + 15) / 16) * 16;
    int* bcnt = (int*)p;                     p += 512 * 4;
    int* boff = (int*)p;                     p += 513 * 4;
    int* bcur = (int*)p;                     p += 512 * 4;

    const int* srcI = ei;
    const int* dstI = ei + E;

    const int NB = (N + 255) / 256;
    const int ET = (E + 4095) / 4096;

    // CSR build (bucketed, no scattered global writes)
    (void)hipMemsetAsync(bcnt, 0, 512 * 4, stream);
    bucket_hist<<<ET, 256, 0, stream>>>(dstI, bcnt, E, nb);
    scan_buckets<<<1, 512, 0, stream>>>(bcnt, boff, bcur, rowptr, nb, N);
    bucket_scatter<<<ET, 256, 0, stream>>>(srcI, dstI, bcur, staging, E, nb);
    bucket_build<<<nb, 256, 0, stream>>>(staging, boff, rowptr, col, N);

    // weight packing: slot 0 = conv1_W2, slots 1..NL = convs_W1, 1+NL.. = convs_W2
    pack_W_all<<<(1 + 2 * NL) * 64, 256, 0, stream>>>(c1W2, csW1, csW2, Wp, NL);

    const int GEMMB = (N + 127) / 128;
    const int AGGB = ((N + 3) / 4 + 3) / 4;

    // layer 1 (input dim 2)
    agg2<<<NB, 256, 0, stream>>>(x, rowptr, col, sum2, N);
    mlp1a<<<(N * 128 + 255) / 256, 256, 0, stream>>>(sum2, c1W1, c1b1, tmp, N);
    gemm_one<<<GEMMB, 256, 0, stream>>>(tmp, Wp, c1b2, c1g, c1be, c1m, c1v, h, N);

    // layers 2..5 (fused MLP)
    for (int i = 0; i < NL; ++i) {
        aggH_bf16<<<AGGB, 256, 0, stream>>>((const uint4*)h, rowptr, col, (uint4*)sum, N);
        gin_mlp<<<GEMMB, 256, 0, stream>>>(sum,
                                           Wp + (size_t)(1 + i) * 16384, csb1 + i * 128,
                                           Wp + (size_t)(1 + NL + i) * 16384, csb2 + i * 128,
                                           csg + i * 128, csbe + i * 128, csm + i * 128,
                                           csv + i * 128, h, N);
    }

    pool_head<<<G, 128, 0, stream>>>(h, batch, lin1W, lin1b, lin2W, lin2b, (float*)d_out, N);
}

// Round 6
// 406.139 us; speedup vs baseline: 2.1512x; 1.0367x over previous
//
#include <hip/hip_runtime.h>

// ---------------------------------------------------------------------------
// GIN inference, round 5:
//  - pooling split: parallel run-accumulate (32-node chunks, fp32 atomics into
//    G x 128 table) + tiny head kernel  [R4: pool_head was 45.6us at 8% occ]
//  - aggregation inner loop unrolled 8x (more gathers in flight)
//  - rest unchanged from R4 (bucketed CSR, permuted layout, fused MLP)
// ---------------------------------------------------------------------------

typedef __attribute__((ext_vector_type(8))) short short8;   // 8 bf16 (4 VGPRs)
typedef __attribute__((ext_vector_type(4))) float floatx4;  // 4 fp32 acc

__device__ __forceinline__ unsigned f2bf(float f) {
    unsigned u = __float_as_uint(f);
    return (u + 0x7fffu + ((u >> 16) & 1u)) >> 16;   // RNE
}
__device__ __forceinline__ float bf2f(unsigned short b) {
    return __uint_as_float(((unsigned)b) << 16);
}
__device__ __forceinline__ float bflo(unsigned u) { return __uint_as_float(u << 16); }
__device__ __forceinline__ float bfhi(unsigned u) { return __uint_as_float(u & 0xffff0000u); }

__device__ __forceinline__ uint4 pack8bf(const float* v) {
    uint4 o;
    o.x = f2bf(v[0]) | (f2bf(v[1]) << 16);
    o.y = f2bf(v[2]) | (f2bf(v[3]) << 16);
    o.z = f2bf(v[4]) | (f2bf(v[5]) << 16);
    o.w = f2bf(v[6]) | (f2bf(v[7]) << 16);
    return o;
}

// ======================= bucketed CSR build =======================

__global__ void bucket_hist(const int* __restrict__ dstA, int* __restrict__ bcnt,
                            int E, int nb) {
    __shared__ int hist[512];
    int tid = threadIdx.x;
    int start = blockIdx.x * 4096;
    for (int i = tid; i < 512; i += 256) hist[i] = 0;
    __syncthreads();
#pragma unroll
    for (int t = 0; t < 16; ++t) {
        int e = start + t * 256 + tid;
        if (e < E) atomicAdd(&hist[dstA[e] >> 7], 1);
    }
    __syncthreads();
    for (int i = tid; i < nb; i += 256)
        if (hist[i]) atomicAdd(&bcnt[i], hist[i]);
}

__global__ void scan_buckets(const int* __restrict__ bcnt, int* __restrict__ boff,
                             int* __restrict__ bcur, int* __restrict__ rowptr,
                             int nb, int N) {
    __shared__ int sa[512], sb[512];
    int t = threadIdx.x;
    sa[t] = (t < nb) ? bcnt[t] : 0;
    __syncthreads();
    int* ps = sa;
    int* pd = sb;
    for (int o = 1; o < 512; o <<= 1) {
        pd[t] = ps[t] + ((t >= o) ? ps[t - o] : 0);
        __syncthreads();
        int* tmp = ps; ps = pd; pd = tmp;
    }
    if (t <= nb) boff[t] = (t == 0) ? 0 : ps[t - 1];
    if (t < nb) bcur[t] = (t == 0) ? 0 : ps[t - 1];
    if (t == 0) rowptr[N] = ps[nb - 1];
}

__global__ void bucket_scatter(const int* __restrict__ srcA, const int* __restrict__ dstA,
                               int* __restrict__ bcur, unsigned* __restrict__ staging,
                               int E, int nb) {
    __shared__ int hist[512];
    __shared__ int sa[512], sb[512];
    __shared__ int toff[513];
    __shared__ int gbase[512];
    __shared__ unsigned pk[4096];
    int tid = threadIdx.x;
    int start = blockIdx.x * 4096;
    for (int i = tid; i < 512; i += 256) hist[i] = 0;
    __syncthreads();
    int bidx[16], rank[16];
    unsigned pval[16];
#pragma unroll
    for (int t = 0; t < 16; ++t) {
        int e = start + t * 256 + tid;
        bidx[t] = -1;
        if (e < E) {
            int d = dstA[e];
            int s = srcA[e];
            int b = d >> 7;
            bidx[t] = b;
            rank[t] = atomicAdd(&hist[b], 1);
            pval[t] = ((unsigned)s << 7) | (unsigned)(d & 127);
        }
    }
    __syncthreads();
    sa[tid] = hist[tid];
    sa[tid + 256] = hist[tid + 256];
    __syncthreads();
    int* ps = sa;
    int* pd = sb;
    for (int o = 1; o < 512; o <<= 1) {
        pd[tid] = ps[tid] + ((tid >= o) ? ps[tid - o] : 0);
        int j2 = tid + 256;
        pd[j2] = ps[j2] + ((j2 >= o) ? ps[j2 - o] : 0);
        __syncthreads();
        int* tmp = ps; ps = pd; pd = tmp;
    }
    toff[tid + 1] = ps[tid];
    toff[tid + 257] = ps[tid + 256];
    if (tid == 0) toff[0] = 0;
    __syncthreads();
    for (int b = tid; b < nb; b += 256) {
        int c = hist[b];
        gbase[b] = c ? atomicAdd(&bcur[b], c) : 0;
    }
#pragma unroll
    for (int t = 0; t < 16; ++t)
        if (bidx[t] >= 0) pk[toff[bidx[t]] + rank[t]] = pval[t];
    __syncthreads();
    int total = toff[512];
    for (int i = tid; i < total; i += 256) {
        int lo = 0, hi = 512;
        while (hi - lo > 1) {
            int mid = (lo + hi) >> 1;
            if (toff[mid] <= i) lo = mid; else hi = mid;
        }
        staging[gbase[lo] + (i - toff[lo])] = pk[i];
    }
}

__global__ void bucket_build(const unsigned* __restrict__ staging, const int* __restrict__ boff,
                             int* __restrict__ rowptr, int* __restrict__ col, int N) {
    __shared__ int deg[128], sca[128], scb[128], curL[128];
    __shared__ unsigned pk[4096];
    __shared__ int colL[4096];
    int b = blockIdx.x, tid = threadIdx.x;
    int lo = boff[b], hi = boff[b + 1];
    int cnt = hi - lo;
    if (cnt > 4096) cnt = 4096;
    for (int i = tid; i < cnt; i += 256) pk[i] = staging[lo + i];
    if (tid < 128) deg[tid] = 0;
    __syncthreads();
    for (int i = tid; i < cnt; i += 256) atomicAdd(&deg[pk[i] & 127u], 1);
    __syncthreads();
    if (tid < 128) sca[tid] = deg[tid];
    __syncthreads();
    int* ps = sca;
    int* pd = scb;
    for (int o = 1; o < 128; o <<= 1) {
        if (tid < 128) pd[tid] = ps[tid] + ((tid >= o) ? ps[tid - o] : 0);
        __syncthreads();
        int* tmp = ps; ps = pd; pd = tmp;
    }
    if (tid < 128) {
        int excl = tid ? ps[tid - 1] : 0;
        curL[tid] = excl;
        int node = b * 128 + tid;
        if (node < N) rowptr[node] = lo + excl;
    }
    __syncthreads();
    for (int i = tid; i < cnt; i += 256) {
        unsigned v = pk[i];
        int p = atomicAdd(&curL[v & 127u], 1);
        colL[p] = (int)(v >> 7);
    }
    __syncthreads();
    for (int i = tid; i < cnt; i += 256) col[lo + i] = colL[i];
}

// ======================= weight packing (perm-aware) =======================

__global__ void pack_W_all(const float* __restrict__ c1W2, const float* __restrict__ csW1,
                           const float* __restrict__ csW2, unsigned short* __restrict__ Wp,
                           int NL) {
    int slot = blockIdx.x >> 6;
    int r = (blockIdx.x & 63) * 256 + threadIdx.x;   // 0..16383
    const float* W = (slot == 0) ? c1W2
                   : (slot <= NL ? csW1 + (size_t)(slot - 1) * 16384
                                 : csW2 + (size_t)(slot - 1 - NL) * 16384);
    int j = r & 7, lane = (r >> 3) & 63, nt = (r >> 9) & 7, ks = (r >> 12) & 3;
    int u = ks * 32 + (lane >> 4) * 8 + j;
    int k = (u & 7) * 16 + (u >> 3);                 // pi(u)
    int n = nt * 16 + (lane & 15);
    Wp[(size_t)slot * 16384 + r] = (unsigned short)f2bf(W[k * 128 + n]);
}

// ======================= layer 1 (input dim = 2) =======================

__global__ void agg2(const float* __restrict__ x, const int* __restrict__ rowptr,
                     const int* __restrict__ col, float* __restrict__ sum2, int N) {
    int n = blockIdx.x * 256 + threadIdx.x;
    if (n >= N) return;
    const float2* x2 = (const float2*)x;
    float2 self = x2[n];
    float ax = self.x, ay = self.y;
    int e0 = rowptr[n], e1 = rowptr[n + 1];
    for (int j = e0; j < e1; ++j) {
        float2 v = x2[col[j]];
        ax += v.x;
        ay += v.y;
    }
    sum2[2 * n] = ax;
    sum2[2 * n + 1] = ay;
}

__global__ void mlp1a(const float* __restrict__ sum2, const float* __restrict__ W1,
                      const float* __restrict__ b1, unsigned short* __restrict__ out, int N) {
    int idx = blockIdx.x * 256 + threadIdx.x;
    if (idx >= N * 128) return;
    int n = idx >> 7, p = idx & 127;
    int c = (p & 7) * 16 + (p >> 3);
    float v = fmaf(sum2[2 * n], W1[c], fmaf(sum2[2 * n + 1], W1[128 + c], b1[c]));
    out[idx] = (unsigned short)f2bf(fmaxf(v, 0.f));
}

// ======================= aggregation (layout-agnostic) =======================

__device__ __forceinline__ void addrow(float* acc, uint4 v) {
    acc[0] += bflo(v.x); acc[1] += bfhi(v.x);
    acc[2] += bflo(v.y); acc[3] += bfhi(v.y);
    acc[4] += bflo(v.z); acc[5] += bfhi(v.z);
    acc[6] += bflo(v.w); acc[7] += bfhi(v.w);
}

__global__ void aggH_bf16(const uint4* __restrict__ h4, const int* __restrict__ rowptr,
                          const int* __restrict__ col, uint4* __restrict__ out4, int N) {
    int wave = (blockIdx.x * blockDim.x + threadIdx.x) >> 6;
    int lane = threadIdx.x & 63;
    int sub = lane >> 4, sl = lane & 15;
    int n = wave * 4 + sub;
    if (n >= N) return;
    size_t base = (size_t)n * 16 + sl;
    uint4 self = h4[base];
    float acc[8];
    acc[0] = bflo(self.x); acc[1] = bfhi(self.x);
    acc[2] = bflo(self.y); acc[3] = bfhi(self.y);
    acc[4] = bflo(self.z); acc[5] = bfhi(self.z);
    acc[6] = bflo(self.w); acc[7] = bfhi(self.w);
    int e0 = rowptr[n], e1 = rowptr[n + 1];
    int j = e0;
    for (; j + 8 <= e1; j += 8) {
        int s[8];
#pragma unroll
        for (int t = 0; t < 8; ++t) s[t] = col[j + t];
        uint4 v[8];
#pragma unroll
        for (int t = 0; t < 8; ++t) v[t] = h4[(size_t)s[t] * 16 + sl];
#pragma unroll
        for (int t = 0; t < 8; ++t) addrow(acc, v[t]);
    }
    for (; j + 4 <= e1; j += 4) {
        int s0 = col[j], s1 = col[j + 1], s2 = col[j + 2], s3 = col[j + 3];
        uint4 v0 = h4[(size_t)s0 * 16 + sl];
        uint4 v1 = h4[(size_t)s1 * 16 + sl];
        uint4 v2 = h4[(size_t)s2 * 16 + sl];
        uint4 v3 = h4[(size_t)s3 * 16 + sl];
        addrow(acc, v0);
        addrow(acc, v1);
        addrow(acc, v2);
        addrow(acc, v3);
    }
    for (; j < e1; ++j) addrow(acc, h4[(size_t)col[j] * 16 + sl]);
    uint4 o;
    o.x = f2bf(acc[0]) | (f2bf(acc[1]) << 16);
    o.y = f2bf(acc[2]) | (f2bf(acc[3]) << 16);
    o.z = f2bf(acc[4]) | (f2bf(acc[5]) << 16);
    o.w = f2bf(acc[6]) | (f2bf(acc[7]) << 16);
    out4[base] = o;
}

// ======================= fused GIN MLP =======================

__launch_bounds__(256)
__global__ void gin_mlp(const unsigned short* __restrict__ A,
                        const unsigned short* __restrict__ W1p, const float* __restrict__ b1,
                        const unsigned short* __restrict__ W2p, const float* __restrict__ b2,
                        const float* __restrict__ gamma, const float* __restrict__ beta,
                        const float* __restrict__ mean, const float* __restrict__ var,
                        unsigned short* __restrict__ out, int N) {
    __shared__ unsigned short hbuf[4][32][136];   // 272B row stride: <=2-way bank conflicts
    int wave = threadIdx.x >> 6, lane = threadIdx.x & 63;
    int row0 = blockIdx.x * 128 + wave * 32;
    if (row0 >= N) return;
    int m = lane & 15, q = lane >> 4;
    int ra = row0 + m;      if (ra > N - 1) ra = N - 1;
    int rb = row0 + 16 + m; if (rb > N - 1) rb = N - 1;

    short8 a0[4], a1[4];
#pragma unroll
    for (int ks = 0; ks < 4; ++ks) {
        a0[ks] = *(const short8*)&A[(size_t)ra * 128 + ks * 32 + q * 8];
        a1[ks] = *(const short8*)&A[(size_t)rb * 128 + ks * 32 + q * 8];
    }

    floatx4 c0[8], c1[8];
#pragma unroll
    for (int nt = 0; nt < 8; ++nt) {
        c0[nt] = (floatx4){0.f, 0.f, 0.f, 0.f};
        c1[nt] = (floatx4){0.f, 0.f, 0.f, 0.f};
    }
#pragma unroll
    for (int nt = 0; nt < 8; ++nt) {
        short8 w0 = *(const short8*)&W1p[((0 * 8 + nt) * 64 + lane) * 8];
        short8 w1 = *(const short8*)&W1p[((1 * 8 + nt) * 64 + lane) * 8];
        short8 w2 = *(const short8*)&W1p[((2 * 8 + nt) * 64 + lane) * 8];
        short8 w3 = *(const short8*)&W1p[((3 * 8 + nt) * 64 + lane) * 8];
        c0[nt] = __builtin_amdgcn_mfma_f32_16x16x32_bf16(a0[0], w0, c0[nt], 0, 0, 0);
        c1[nt] = __builtin_amdgcn_mfma_f32_16x16x32_bf16(a1[0], w0, c1[nt], 0, 0, 0);
        c0[nt] = __builtin_amdgcn_mfma_f32_16x16x32_bf16(a0[1], w1, c0[nt], 0, 0, 0);
        c1[nt] = __builtin_amdgcn_mfma_f32_16x16x32_bf16(a1[1], w1, c1[nt], 0, 0, 0);
        c0[nt] = __builtin_amdgcn_mfma_f32_16x16x32_bf16(a0[2], w2, c0[nt], 0, 0, 0);
        c1[nt] = __builtin_amdgcn_mfma_f32_16x16x32_bf16(a1[2], w2, c1[nt], 0, 0, 0);
        c0[nt] = __builtin_amdgcn_mfma_f32_16x16x32_bf16(a0[3], w3, c0[nt], 0, 0, 0);
        c1[nt] = __builtin_amdgcn_mfma_f32_16x16x32_bf16(a1[3], w3, c1[nt], 0, 0, 0);
    }

    float b1v[8];
#pragma unroll
    for (int nt = 0; nt < 8; ++nt) b1v[nt] = b1[nt * 16 + m];
#pragma unroll
    for (int rg = 0; rg < 4; ++rg) {
        float v0[8], v1[8];
#pragma unroll
        for (int nt = 0; nt < 8; ++nt) {
            v0[nt] = fmaxf(c0[nt][rg] + b1v[nt], 0.f);
            v1[nt] = fmaxf(c1[nt][rg] + b1v[nt], 0.f);
        }
        *(uint4*)&hbuf[wave][q * 4 + rg][m * 8] = pack8bf(v0);
        *(uint4*)&hbuf[wave][16 + q * 4 + rg][m * 8] = pack8bf(v1);
    }

    short8 d0[4], d1[4];
#pragma unroll
    for (int ks = 0; ks < 4; ++ks) {
        d0[ks] = *(const short8*)&hbuf[wave][m][ks * 32 + q * 8];
        d1[ks] = *(const short8*)&hbuf[wave][16 + m][ks * 32 + q * 8];
    }

    floatx4 e0[8], e1[8];
#pragma unroll
    for (int nt = 0; nt < 8; ++nt) {
        e0[nt] = (floatx4){0.f, 0.f, 0.f, 0.f};
        e1[nt] = (floatx4){0.f, 0.f, 0.f, 0.f};
    }
#pragma unroll
    for (int nt = 0; nt < 8; ++nt) {
        short8 w0 = *(const short8*)&W2p[((0 * 8 + nt) * 64 + lane) * 8];
        short8 w1 = *(const short8*)&W2p[((1 * 8 + nt) * 64 + lane) * 8];
        short8 w2 = *(const short8*)&W2p[((2 * 8 + nt) * 64 + lane) * 8];
        short8 w3 = *(const short8*)&W2p[((3 * 8 + nt) * 64 + lane) * 8];
        e0[nt] = __builtin_amdgcn_mfma_f32_16x16x32_bf16(d0[0], w0, e0[nt], 0, 0, 0);
        e1[nt] = __builtin_amdgcn_mfma_f32_16x16x32_bf16(d1[0], w0, e1[nt], 0, 0, 0);
        e0[nt] = __builtin_amdgcn_mfma_f32_16x16x32_bf16(d0[1], w1, e0[nt], 0, 0, 0);
        e1[nt] = __builtin_amdgcn_mfma_f32_16x16x32_bf16(d1[1], w1, e1[nt], 0, 0, 0);
        e0[nt] = __builtin_amdgcn_mfma_f32_16x16x32_bf16(d0[2], w2, e0[nt], 0, 0, 0);
        e1[nt] = __builtin_amdgcn_mfma_f32_16x16x32_bf16(d1[2], w2, e1[nt], 0, 0, 0);
        e0[nt] = __builtin_amdgcn_mfma_f32_16x16x32_bf16(d0[3], w3, e0[nt], 0, 0, 0);
        e1[nt] = __builtin_amdgcn_mfma_f32_16x16x32_bf16(d1[3], w3, e1[nt], 0, 0, 0);
    }

    float b2v[8], scl[8], shf[8];
#pragma unroll
    for (int nt = 0; nt < 8; ++nt) {
        int c = nt * 16 + m;
        b2v[nt] = b2[c];
        float s = gamma[c] * rsqrtf(var[c] + 1e-5f);
        scl[nt] = s;
        shf[nt] = beta[c] - mean[c] * s;
    }
#pragma unroll
    for (int rg = 0; rg < 4; ++rg) {
        int r0 = row0 + q * 4 + rg;
        int r1 = row0 + 16 + q * 4 + rg;
        float v0[8], v1[8];
#pragma unroll
        for (int nt = 0; nt < 8; ++nt) {
            v0[nt] = fmaf(fmaxf(e0[nt][rg] + b2v[nt], 0.f), scl[nt], shf[nt]);
            v1[nt] = fmaf(fmaxf(e1[nt][rg] + b2v[nt], 0.f), scl[nt], shf[nt]);
        }
        if (r0 < N) *(uint4*)&out[(size_t)r0 * 128 + m * 8] = pack8bf(v0);
        if (r1 < N) *(uint4*)&out[(size_t)r1 * 128 + m * 8] = pack8bf(v1);
    }
}

// ======================= layer-1 single GEMM (W2 + bias + relu + BN) ========

__launch_bounds__(256)
__global__ void gemm_one(const unsigned short* __restrict__ A,
                         const unsigned short* __restrict__ Wp,
                         const float* __restrict__ bias,
                         const float* __restrict__ gamma, const float* __restrict__ beta,
                         const float* __restrict__ mean, const float* __restrict__ var,
                         unsigned short* __restrict__ out, int N) {
    int wave = threadIdx.x >> 6, lane = threadIdx.x & 63;
    int row0 = blockIdx.x * 128 + wave * 32;
    if (row0 >= N) return;
    int m = lane & 15, q = lane >> 4;
    int ra = row0 + m;      if (ra > N - 1) ra = N - 1;
    int rb = row0 + 16 + m; if (rb > N - 1) rb = N - 1;

    short8 a0[4], a1[4];
#pragma unroll
    for (int ks = 0; ks < 4; ++ks) {
        a0[ks] = *(const short8*)&A[(size_t)ra * 128 + ks * 32 + q * 8];
        a1[ks] = *(const short8*)&A[(size_t)rb * 128 + ks * 32 + q * 8];
    }
    floatx4 c0[8], c1[8];
#pragma unroll
    for (int nt = 0; nt < 8; ++nt) {
        c0[nt] = (floatx4){0.f, 0.f, 0.f, 0.f};
        c1[nt] = (floatx4){0.f, 0.f, 0.f, 0.f};
    }
#pragma unroll
    for (int nt = 0; nt < 8; ++nt) {
        short8 w0 = *(const short8*)&Wp[((0 * 8 + nt) * 64 + lane) * 8];
        short8 w1 = *(const short8*)&Wp[((1 * 8 + nt) * 64 + lane) * 8];
        short8 w2 = *(const short8*)&Wp[((2 * 8 + nt) * 64 + lane) * 8];
        short8 w3 = *(const short8*)&Wp[((3 * 8 + nt) * 64 + lane) * 8];
        c0[nt] = __builtin_amdgcn_mfma_f32_16x16x32_bf16(a0[0], w0, c0[nt], 0, 0, 0);
        c1[nt] = __builtin_amdgcn_mfma_f32_16x16x32_bf16(a1[0], w0, c1[nt], 0, 0, 0);
        c0[nt] = __builtin_amdgcn_mfma_f32_16x16x32_bf16(a0[1], w1, c0[nt], 0, 0, 0);
        c1[nt] = __builtin_amdgcn_mfma_f32_16x16x32_bf16(a1[1], w1, c1[nt], 0, 0, 0);
        c0[nt] = __builtin_amdgcn_mfma_f32_16x16x32_bf16(a0[2], w2, c0[nt], 0, 0, 0);
        c1[nt] = __builtin_amdgcn_mfma_f32_16x16x32_bf16(a1[2], w2, c1[nt], 0, 0, 0);
        c0[nt] = __builtin_amdgcn_mfma_f32_16x16x32_bf16(a0[3], w3, c0[nt], 0, 0, 0);
        c1[nt] = __builtin_amdgcn_mfma_f32_16x16x32_bf16(a1[3], w3, c1[nt], 0, 0, 0);
    }
    float bv[8], scl[8], shf[8];
#pragma unroll
    for (int nt = 0; nt < 8; ++nt) {
        int c = nt * 16 + m;
        bv[nt] = bias[c];
        float s = gamma[c] * rsqrtf(var[c] + 1e-5f);
        scl[nt] = s;
        shf[nt] = beta[c] - mean[c] * s;
    }
#pragma unroll
    for (int rg = 0; rg < 4; ++rg) {
        int r0 = row0 + q * 4 + rg;
        int r1 = row0 + 16 + q * 4 + rg;
        float v0[8], v1[8];
#pragma unroll
        for (int nt = 0; nt < 8; ++nt) {
            v0[nt] = fmaf(fmaxf(c0[nt][rg] + bv[nt], 0.f), scl[nt], shf[nt]);
            v1[nt] = fmaf(fmaxf(c1[nt][rg] + bv[nt], 0.f), scl[nt], shf[nt]);
        }
        if (r0 < N) *(uint4*)&out[(size_t)r0 * 128 + m * 8] = pack8bf(v0);
        if (r1 < N) *(uint4*)&out[(size_t)r1 * 128 + m * 8] = pack8bf(v1);
    }
}

// ======================= pooling: parallel partial sums + head ==============
// pool_partial: 32-node chunks, thread c accumulates column c over sorted-batch
// runs, flushing one fp32 atomicAdd per (graph-run, column).

__global__ void pool_partial(const unsigned short* __restrict__ h,
                             const int* __restrict__ batch,
                             float* __restrict__ pooled, int N) {
    int c = threadIdx.x;              // 0..127
    int n0 = blockIdx.x * 32;
    int n1 = n0 + 32; if (n1 > N) n1 = N;
    if (n0 >= N) return;
    int cg = batch[n0];
    float acc = 0.f;
    for (int n = n0; n < n1; ++n) {
        int g = batch[n];
        if (g != cg) {
            atomicAdd(&pooled[(size_t)cg * 128 + c], acc);
            acc = 0.f;
            cg = g;
        }
        acc += bf2f(h[(size_t)n * 128 + c]);
    }
    atomicAdd(&pooled[(size_t)cg * 128 + c], acc);
}

__global__ void head(const float* __restrict__ pooled,
                     const float* __restrict__ lin1W, const float* __restrict__ lin1b,
                     const float* __restrict__ lin2W, const float* __restrict__ lin2b,
                     float* __restrict__ out) {
    int g = blockIdx.x;
    int c = threadIdx.x;  // 0..127
    __shared__ float pl[128];
    pl[c] = pooled[(size_t)g * 128 + c];
    __syncthreads();

    float o = lin1b[c];
    for (int k = 0; k < 128; ++k) {
        int ko = (k & 7) * 16 + (k >> 3);   // orig col held at permuted position k
        o = fmaf(pl[k], lin1W[ko * 128 + c], o);
    }
    o = fmaxf(o, 0.f) * lin2W[c];

    __shared__ float red[128];
    red[c] = o;
    __syncthreads();
    for (int off = 64; off > 0; off >>= 1) {
        if (c < off) red[c] += red[c + off];
        __syncthreads();
    }
    if (c == 0) out[g] = red[0] + lin2b[0];
}

// ---------------------------------------------------------------------------

extern "C" void kernel_launch(void* const* d_in, const int* in_sizes, int n_in,
                              void* d_out, int out_size, void* d_ws, size_t ws_size,
                              hipStream_t stream) {
    const float* x     = (const float*)d_in[0];
    const int*   ei    = (const int*)d_in[1];
    const int*   batch = (const int*)d_in[2];
    const float* c1W1  = (const float*)d_in[3];
    const float* c1b1  = (const float*)d_in[4];
    const float* c1W2  = (const float*)d_in[5];
    const float* c1b2  = (const float*)d_in[6];
    const float* c1g   = (const float*)d_in[7];
    const float* c1be  = (const float*)d_in[8];
    const float* c1m   = (const float*)d_in[9];
    const float* c1v   = (const float*)d_in[10];
    const float* csW1  = (const float*)d_in[11];
    const float* csb1  = (const float*)d_in[12];
    const float* csW2  = (const float*)d_in[13];
    const float* csb2  = (const float*)d_in[14];
    const float* csg   = (const float*)d_in[15];
    const float* csbe  = (const float*)d_in[16];
    const float* csm   = (const float*)d_in[17];
    const float* csv   = (const float*)d_in[18];
    const float* lin1W = (const float*)d_in[19];
    const float* lin1b = (const float*)d_in[20];
    const float* lin2W = (const float*)d_in[21];
    const float* lin2b = (const float*)d_in[22];

    const int N = in_sizes[0] / 2;
    const int E = in_sizes[1] / 2;
    const int G = out_size;
    const int NL = in_sizes[11] / (128 * 128);  // 4
    const int nb = (N + 127) >> 7;              // buckets of 128 nodes

    char* ws = (char*)d_ws;
    size_t HS = (size_t)N * 128 * sizeof(unsigned short);      // bf16 feature plane
    unsigned short* h   = (unsigned short*)(ws);
    unsigned short* sum = (unsigned short*)(ws + HS);
    unsigned short* tmp = (unsigned short*)(ws + 2 * HS);
    char* p = ws + 3 * HS;
    float* sum2 = (float*)p;                 p += (((size_t)N * 2 * 4 + 15) / 16) * 16;
    unsigned short* Wp = (unsigned short*)p; p += ((9 * 16384 * 2 + 15) / 16) * 16;
    int* rowptr = (int*)p;                   p += (((size_t)(N + 1) * 4 + 15) / 16) * 16;
    int* col = (int*)p;                      p += (((size_t)E * 4 + 15) / 16) * 16;
    unsigned* staging = (unsigned*)p;        p += (((size_t)E * 4 + 15) / 16) * 16;
    int* bcnt = (int*)p;                     p += 512 * 4;
    int* boff = (int*)p;                     p += 513 * 4;
    int* bcur = (int*)p;                     p += 512 * 4;
    float* pooled = (float*)p;               p += (size_t)G * 128 * 4;

    const int* srcI = ei;
    const int* dstI = ei + E;

    const int NB = (N + 255) / 256;
    const int ET = (E + 4095) / 4096;

    // CSR build (bucketed, no scattered global writes)
    (void)hipMemsetAsync(bcnt, 0, 512 * 4, stream);
    (void)hipMemsetAsync(pooled, 0, (size_t)G * 128 * 4, stream);
    bucket_hist<<<ET, 256, 0, stream>>>(dstI, bcnt, E, nb);
    scan_buckets<<<1, 512, 0, stream>>>(bcnt, boff, bcur, rowptr, nb, N);
    bucket_scatter<<<ET, 256, 0, stream>>>(srcI, dstI, bcur, staging, E, nb);
    bucket_build<<<nb, 256, 0, stream>>>(staging, boff, rowptr, col, N);

    // weight packing
    pack_W_all<<<(1 + 2 * NL) * 64, 256, 0, stream>>>(c1W2, csW1, csW2, Wp, NL);

    const int GEMMB = (N + 127) / 128;
    const int AGGB = ((N + 3) / 4 + 3) / 4;

    // layer 1 (input dim 2)
    agg2<<<NB, 256, 0, stream>>>(x, rowptr, col, sum2, N);
    mlp1a<<<(N * 128 + 255) / 256, 256, 0, stream>>>(sum2, c1W1, c1b1, tmp, N);
    gemm_one<<<GEMMB, 256, 0, stream>>>(tmp, Wp, c1b2, c1g, c1be, c1m, c1v, h, N);

    // layers 2..5 (fused MLP)
    for (int i = 0; i < NL; ++i) {
        aggH_bf16<<<AGGB, 256, 0, stream>>>((const uint4*)h, rowptr, col, (uint4*)sum, N);
        gin_mlp<<<GEMMB, 256, 0, stream>>>(sum,
                                           Wp + (size_t)(1 + i) * 16384, csb1 + i * 128,
                                           Wp + (size_t)(1 + NL + i) * 16384, csb2 + i * 128,
                                           csg + i * 128, csbe + i * 128, csm + i * 128,
                                           csv + i * 128, h, N);
    }

    // pooling + head
    pool_partial<<<(N + 31) / 32, 128, 0, stream>>>(h, batch, pooled, N);
    head<<<G, 128, 0, stream>>>(pooled, lin1W, lin1b, lin2W, lin2b, (float*)d_out);
}